// Round 8
// baseline (287.588 us; speedup 1.0000x reference)
//
#include <hip/hip_runtime.h>
#include <stdint.h>
#include <math.h>

#define CTX 2048
#define DM  2048
#define NH  16
#define HD  128

typedef __attribute__((ext_vector_type(8))) short short8;   // 8 x bf16 (4 VGPRs)
typedef __attribute__((ext_vector_type(4))) float f32x4;    // MFMA acc
typedef unsigned short u16;

__device__ __forceinline__ u16 f2bf(float f) {
    unsigned u = __float_as_uint(f);
    unsigned r = u + 0x7fffu + ((u >> 16) & 1u);   // RTNE
    return (u16)(r >> 16);
}
__device__ __forceinline__ float bf2f(u16 h) {
    return __uint_as_float(((unsigned)h) << 16);
}

// Opaque LDS read: invisible to SIInsertWaitcnts' LDS-DMA alias tracking, so
// the compiler cannot insert vmcnt(0) drains before it. Ordering enforced
// manually: counted lgkmcnt + sched_barrier(0) before every consumer (rule #18).
__device__ __forceinline__ short8 ds_read_b128_o(const void* p) {
    short8 r;
    asm volatile("ds_read_b128 %0, %1"
                 : "=v"(r)
                 : "v"((const __attribute__((address_space(3))) void*)p));
    return r;
}

// ------- merged weight transpose + f32->bf16 (W[K][N] -> WT[N][K]), 4 slabs ---
__global__ __launch_bounds__(256)
void transpose_all_kernel(const float* __restrict__ Wq, const float* __restrict__ Wo,
                          const float* __restrict__ Wkv,
                          u16* __restrict__ WqT, u16* __restrict__ WoT, u16* __restrict__ WkvT)
{
    __shared__ float tile[32][33];
    int z = blockIdx.z;
    const float* S; u16* D; int nsrc, c0, r0;
    if (z == 0)      { S = Wq;  D = WqT;  nsrc = DM;     c0 = 0;  r0 = 0;    }
    else if (z == 1) { S = Wo;  D = WoT;  nsrc = DM;     c0 = 0;  r0 = 0;    }
    else if (z == 2) { S = Wkv; D = WkvT; nsrc = 2 * DM; c0 = 0;  r0 = 0;    }
    else             { S = Wkv; D = WkvT; nsrc = 2 * DM; c0 = DM; r0 = DM;   }
    int k0 = blockIdx.x * 32, n0 = blockIdx.y * 32;
    int tx = threadIdx.x, ty = threadIdx.y;          // 32 x 8
#pragma unroll
    for (int j = 0; j < 4; ++j) {
        int kk = ty + 8 * j;
        tile[kk][tx] = S[(size_t)(k0 + kk) * nsrc + c0 + n0 + tx];
    }
    __syncthreads();
#pragma unroll
    for (int j = 0; j < 4; ++j) {
        int nn = ty + 8 * j;
        D[(size_t)(r0 + n0 + nn) * DM + k0 + tx] = f2bf(tile[tx][nn]);
    }
}

// -------- LN stats + normalized A matrices (bf16) + rotary factor table -------
__global__ __launch_bounds__(256)
void ln_stats_kernel(const float* __restrict__ x,
                     const float* __restrict__ qg, const float* __restrict__ qb,
                     const float* __restrict__ kg, const float* __restrict__ kb,
                     u16* __restrict__ Aq, u16* __restrict__ Akv, float* __restrict__ ftab)
{
    int c = blockIdx.x, t = threadIdx.x;
    const float* row = x + (size_t)c * DM;
    float4 v0 = *(const float4*)(row + t * 8);
    float4 v1 = *(const float4*)(row + t * 8 + 4);
    float vals[8] = {v0.x, v0.y, v0.z, v0.w, v1.x, v1.y, v1.z, v1.w};
    float s = 0.f, ss = 0.f;
#pragma unroll
    for (int j = 0; j < 8; ++j) { s += vals[j]; ss += vals[j] * vals[j]; }
#pragma unroll
    for (int off = 32; off; off >>= 1) { s += __shfl_xor(s, off); ss += __shfl_xor(ss, off); }
    __shared__ float red[8];
    int w = t >> 6;
    if ((t & 63) == 0) { red[w] = s; red[4 + w] = ss; }
    __syncthreads();
    float st  = red[0] + red[1] + red[2] + red[3];
    float sst = red[4] + red[5] + red[6] + red[7];
    float mu   = st * (1.f / DM);
    float var  = sst * (1.f / DM) - mu * mu;
    float rstd = rsqrtf(var + 1e-5f);
    if (t < 64) {                         // rotary table, m folded in
        const float LT64 = 10.30895266f / 64.f;   // ln(30000)/64
        float m = sqrtf(sst);
        float sn, cs;
        sincosf((float)c * ((float)t * LT64), &sn, &cs);
        float2 wv = {m * cs, m * sn};
        *(float2*)(ftab + ((size_t)c * 64 + t) * 2) = wv;
    }
    short8 aq, akv;
#pragma unroll
    for (int j = 0; j < 8; ++j) {
        int d = t * 8 + j;
        float xh = (vals[j] - mu) * rstd;
        aq[j]  = (short)f2bf(xh * qg[d] + qb[d]);
        akv[j] = (short)f2bf(xh * kg[d] + kb[d]);
    }
    *(short8*)(Aq  + (size_t)c * DM + t * 8) = aq;
    *(short8*)(Akv + (size_t)c * DM + t * 8) = akv;
}

// ---------------- fused QKV projection GEMM -----------------------------------
// v6: 128x256 tile, BK=64, 4 waves (1Mx4N). B fragments now load GLOBAL->REG
// (skipping LDS entirely): the per-lane fragment address equals what the old
// stage+XOR pair resolved to (swizzles cancel). Cuts per-iter LDS traffic
// 144->80 KB, removes B from the lgkm critical path, LDS 48->32 KB (A dbuf).
// B(kt+1) is loaded into the alternating register bank (macro-expanded, no
// runtime indexing) while tile kt computes; end-of-iter vmcnt(8) retires only
// the A-DMA (issued BEFORE the B loads) and leaves B's 8 loads in flight
// across the barrier; the compiler inserts the correctly-counted wait for
// them before next iteration's MFMAs.
//
// Race audit: stageA(kt+1) targets As[buf^1] (not being read). Next iter's
// ds_reads of As[buf^1] are safe: vmcnt(8) retires this wave's 4 A-DMA
// (oldest of the 12 outstanding), barrier makes that block-wide. Stage into
// As[buf] happens next iter only after this iter's a-reads retired (lgkm(0)
// before last MFMA cluster) + barrier.
__global__ __launch_bounds__(256, 2)
void qkv_gemm256_kernel(const u16* __restrict__ Aq, const u16* __restrict__ Akv,
                        const u16* __restrict__ WqT, const u16* __restrict__ WkvT,
                        const float* __restrict__ bq, const float* __restrict__ bkv,
                        u16* __restrict__ Qf, u16* __restrict__ Kf, u16* __restrict__ vT)
{
    __shared__ __align__(16) u16 As[2][128][64];      // 32 KiB double-buffered

    constexpr int NT = DM / 64;                       // 32 K-tiles (even)

    // XCD swizzle: 384 blocks, 48 contiguous per XCD (384 % 8 == 0, bijective)
    int lin = blockIdx.x;
    int swz = (lin & 7) * 48 + (lin >> 3);
    int mt  = swz & 15;         // M tile 0..15 (128 rows)
    int ng  = swz >> 4;         // 0..23
    int seg = ng >> 3;          // 0:Q 1:K 2:V
    int nt  = ng & 7;           // N tile 0..7 (256 cols)

    const u16* Amat; const u16* Bmat; const float* bias; u16* outp; bool rowbias;
    if (seg == 0) {
        Amat = Aq  + (size_t)mt * 128 * DM;
        Bmat = WqT + (size_t)nt * 256 * DM;
        bias = bq + nt * 256;
        outp = Qf + (size_t)mt * 128 * DM + nt * 256;
        rowbias = false;
    } else if (seg == 1) {
        Amat = Akv  + (size_t)mt * 128 * DM;
        Bmat = WkvT + (size_t)nt * 256 * DM;
        bias = bkv + nt * 256;
        outp = Kf + (size_t)mt * 128 * DM + nt * 256;
        rowbias = false;
    } else {
        Amat = WkvT + (size_t)(DM + mt * 128) * DM;   // V dims as GEMM rows
        Bmat = Akv  + (size_t)nt * 256 * DM;          // context as GEMM cols
        bias = bkv + DM + mt * 128;                   // per-row bias
        outp = vT + (size_t)mt * 128 * CTX + nt * 256;
        rowbias = true;
    }

    int tid = threadIdx.x;
    int wid = tid >> 6, l = tid & 63;                 // 4 waves, wave = N slice
    int wc = wid;                                     // 0..3
    int lhi = l >> 4, llo = l & 15;
    int srow  = l >> 3;                               // staging row within 8-row group
    int sunit = (l & 7) ^ srow;                       // inverse-swizzled 16B unit

    auto stageA = [&](int kt, int buf) {
#pragma unroll
        for (int rd = 0; rd < 4; ++rd) {
            int r = wid * 32 + rd * 8;
            const u16* src = Amat + (size_t)(r + srow) * DM + kt * 64 + sunit * 8;
            __builtin_amdgcn_global_load_lds((const __attribute__((address_space(1))) void*)src,
                (__attribute__((address_space(3))) void*)&As[buf][r][0], 16, 0, 0);
        }
    };

    // B fragment base: col = wc*64 + 16*ni + llo, elem k = kt*64 + ks*32 + lhi*8
    const u16* bptr = Bmat + (size_t)(wc * 64 + llo) * DM + lhi * 8;

    f32x4 acc[8][4] = {};                 // accumulator (AGPR side)
    short8 a[4][2];                       // a03 then a47 (reused)
    short8 bA[4][2], bB[4][2];            // alternating B banks

    // prologue: stage A(0), load B(0) -> bA, drain, barrier
    stageA(0, 0);
#pragma unroll
    for (int ni = 0; ni < 4; ++ni)
#pragma unroll
        for (int ks = 0; ks < 2; ++ks)
            bA[ni][ks] = *(const short8*)(bptr + (size_t)ni * 16 * DM + ks * 32);
    asm volatile("s_waitcnt vmcnt(0)" ::: "memory");
    __builtin_amdgcn_s_barrier();

#define QKV_BODY(KT, BC, BN)                                                    \
    {                                                                           \
        const int buf = (KT) & 1;                                               \
        _Pragma("unroll")                                                       \
        for (int mi = 0; mi < 4; ++mi)                                          \
            _Pragma("unroll")                                                   \
            for (int ks = 0; ks < 2; ++ks)                                      \
                a[mi][ks] = ds_read_b128_o(                                     \
                    &As[buf][16 * mi + llo][((ks * 4 + lhi) ^ (llo & 7)) << 3]);\
        if ((KT) + 1 < NT) {                                                    \
            stageA((KT) + 1, buf ^ 1);          /* A-DMA first (oldest) */      \
            _Pragma("unroll")                                                   \
            for (int ni = 0; ni < 4; ++ni)                                      \
                _Pragma("unroll")                                               \
                for (int ks = 0; ks < 2; ++ks)                                  \
                    BN[ni][ks] = *(const short8*)(bptr + (size_t)ni * 16 * DM   \
                                                  + ((KT) + 1) * 64 + ks * 32); \
        }                                                                       \
        asm volatile("s_waitcnt lgkmcnt(0)" ::: "memory");                      \
        __builtin_amdgcn_sched_barrier(0);                                      \
        __builtin_amdgcn_s_setprio(1);                                          \
        _Pragma("unroll")                                                       \
        for (int ks = 0; ks < 2; ++ks)                                          \
            _Pragma("unroll")                                                   \
            for (int mi = 0; mi < 4; ++mi)                                      \
                _Pragma("unroll")                                               \
                for (int ni = 0; ni < 4; ++ni)                                  \
                    acc[mi][ni] = __builtin_amdgcn_mfma_f32_16x16x32_bf16(      \
                        a[mi][ks], BC[ni][ks], acc[mi][ni], 0, 0, 0);           \
        __builtin_amdgcn_s_setprio(0);                                          \
        _Pragma("unroll")                                                       \
        for (int mi = 0; mi < 4; ++mi)                                          \
            _Pragma("unroll")                                                   \
            for (int ks = 0; ks < 2; ++ks)                                      \
                a[mi][ks] = ds_read_b128_o(                                     \
                    &As[buf][16 * (4 + mi) + llo][((ks * 4 + lhi) ^ (llo & 7)) << 3]); \
        asm volatile("s_waitcnt lgkmcnt(0)" ::: "memory");                      \
        __builtin_amdgcn_sched_barrier(0);                                      \
        __builtin_amdgcn_s_setprio(1);                                          \
        _Pragma("unroll")                                                       \
        for (int ks = 0; ks < 2; ++ks)                                          \
            _Pragma("unroll")                                                   \
            for (int mi = 0; mi < 4; ++mi)                                      \
                _Pragma("unroll")                                               \
                for (int ni = 0; ni < 4; ++ni)                                  \
                    acc[4 + mi][ni] = __builtin_amdgcn_mfma_f32_16x16x32_bf16(  \
                        a[mi][ks], BC[ni][ks], acc[4 + mi][ni], 0, 0, 0);       \
        __builtin_amdgcn_s_setprio(0);                                          \
        /* retire the 4 A-DMA (oldest); leave BN's 8 loads in flight */         \
        asm volatile("s_waitcnt vmcnt(8)" ::: "memory");                        \
        __builtin_amdgcn_s_barrier();                                           \
    }

    for (int kt = 0; kt < NT; kt += 2) {
        QKV_BODY(kt,     bA, bB)
        QKV_BODY(kt + 1, bB, bA)
    }
#undef QKV_BODY

    // ---------------- epilogue: bias + bf16 store ----------------------------
    int cbase = 64 * wc;
    if (!rowbias) {
#pragma unroll
        for (int ni = 0; ni < 4; ++ni) {
            float bv = bias[cbase + 16 * ni + llo];
#pragma unroll
            for (int mi = 0; mi < 8; ++mi)
#pragma unroll
                for (int rr = 0; rr < 4; ++rr) {
                    int gr = 16 * mi + 4 * lhi + rr;
                    outp[(size_t)gr * DM + cbase + 16 * ni + llo] = f2bf(acc[mi][ni][rr] + bv);
                }
        }
    } else {
#pragma unroll
        for (int mi = 0; mi < 8; ++mi)
#pragma unroll
            for (int rr = 0; rr < 4; ++rr) {
                int gr = 16 * mi + 4 * lhi + rr;
                float bv = bias[gr];
#pragma unroll
                for (int ni = 0; ni < 4; ++ni)
                    outp[(size_t)gr * CTX + cbase + 16 * ni + llo] = f2bf(acc[mi][ni][rr] + bv);
            }
    }
}

// ---------------- O-projection GEMM: 256^2 tile, 4-way split-K ----------------
__global__ __launch_bounds__(512, 2)
void oproj_gemm256_kernel(const u16* __restrict__ A, const u16* __restrict__ BT,
                          u16* __restrict__ outp)
{
    __shared__ __align__(16) u16 As[2][2][128][64];
    __shared__ __align__(16) u16 Bs[2][2][128][64];

    constexpr int NT = 8;                             // 8 K-tiles = 512 deep

    // XCD swizzle: 256 blocks, 32 contiguous per XCD (256 % 8 == 0, bijective)
    int lin = blockIdx.x;
    int swz = (lin & 7) * 32 + (lin >> 3);
    int kz  = swz >> 6;          // K split 0..3
    int rem = swz & 63;
    int mt  = rem & 7;
    int nt  = rem >> 3;

    const u16* Amat = A  + (size_t)mt * 256 * DM + kz * 512;
    const u16* Bmat = BT + (size_t)nt * 256 * DM + kz * 512;
    u16* out = outp + (size_t)kz * CTX * DM + (size_t)mt * 256 * DM + nt * 256;

    int tid = threadIdx.x;
    int wid = tid >> 6, l = tid & 63;
    int wr = wid >> 2, wc = wid & 3;
    int lhi = l >> 4, llo = l & 15;
    int srow  = l >> 3;
    int sunit = (l & 7) ^ srow;

    auto stageA = [&](int kt, int h) {
#pragma unroll
        for (int rd = 0; rd < 2; ++rd) {
            const u16* src = Amat + (size_t)(h * 128 + rd * 64 + wid * 8 + srow) * DM
                             + kt * 64 + sunit * 8;
            __builtin_amdgcn_global_load_lds((const __attribute__((address_space(1))) void*)src,
                (__attribute__((address_space(3))) void*)&As[kt & 1][h][rd * 64 + wid * 8][0],
                16, 0, 0);
        }
    };
    auto stageB = [&](int kt, int h) {
#pragma unroll
        for (int rd = 0; rd < 2; ++rd) {
            const u16* src = Bmat + (size_t)(h * 128 + rd * 64 + wid * 8 + srow) * DM
                             + kt * 64 + sunit * 8;
            __builtin_amdgcn_global_load_lds((const __attribute__((address_space(1))) void*)src,
                (__attribute__((address_space(3))) void*)&Bs[kt & 1][h][rd * 64 + wid * 8][0],
                16, 0, 0);
        }
    };

    f32x4 acc[8][4] = {};
    short8 a[4][2];
    short8 b0[2][2], b1[2][2];
    int bhalf = wc >> 1, brow = (wc & 1) * 64;

    stageA(0, 0); stageA(0, 1); stageB(0, 0); stageB(0, 1);
    stageA(1, 0); stageA(1, 1); stageB(1, 0); stageB(1, 1);
    asm volatile("s_waitcnt vmcnt(8)" ::: "memory");
    __builtin_amdgcn_s_barrier();

    for (int kt = 0; kt < NT; ++kt) {
        int buf = kt & 1;

#pragma unroll
        for (int ni = 0; ni < 2; ++ni)
#pragma unroll
            for (int ks = 0; ks < 2; ++ks) {
                int r = brow + 16 * ni + llo;
                b0[ni][ks] = ds_read_b128_o(&Bs[buf][bhalf][r][((ks * 4 + lhi) ^ (llo & 7)) << 3]);
            }
#pragma unroll
        for (int mi = 0; mi < 4; ++mi)
#pragma unroll
            for (int ks = 0; ks < 2; ++ks) {
                int r = 16 * mi + llo;
                a[mi][ks] = ds_read_b128_o(&As[buf][wr][r][((ks * 4 + lhi) ^ (llo & 7)) << 3]);
            }
#pragma unroll
        for (int ni = 0; ni < 2; ++ni)
#pragma unroll
            for (int ks = 0; ks < 2; ++ks) {
                int r = brow + 16 * (2 + ni) + llo;
                b1[ni][ks] = ds_read_b128_o(&Bs[buf][bhalf][r][((ks * 4 + lhi) ^ (llo & 7)) << 3]);
            }

        asm volatile("s_waitcnt lgkmcnt(4)" ::: "memory");
        __builtin_amdgcn_sched_barrier(0);
        __builtin_amdgcn_s_setprio(1);
#pragma unroll
        for (int ks = 0; ks < 2; ++ks)
#pragma unroll
            for (int mi = 0; mi < 4; ++mi)
#pragma unroll
                for (int ni = 0; ni < 2; ++ni)
                    acc[mi][ni] = __builtin_amdgcn_mfma_f32_16x16x32_bf16(
                        a[mi][ks], b0[ni][ks], acc[mi][ni], 0, 0, 0);
        __builtin_amdgcn_s_setprio(0);

        asm volatile("s_waitcnt lgkmcnt(0)" ::: "memory");
        __builtin_amdgcn_sched_barrier(0);
        __builtin_amdgcn_s_setprio(1);
#pragma unroll
        for (int ks = 0; ks < 2; ++ks)
#pragma unroll
            for (int mi = 0; mi < 4; ++mi)
#pragma unroll
                for (int ni = 0; ni < 2; ++ni)
                    acc[mi][2 + ni] = __builtin_amdgcn_mfma_f32_16x16x32_bf16(
                        a[mi][ks], b1[ni][ks], acc[mi][2 + ni], 0, 0, 0);
        __builtin_amdgcn_s_setprio(0);

        __builtin_amdgcn_s_barrier();   // #1

        if (kt + 2 < NT) { stageB(kt + 2, 0); stageB(kt + 2, 1); }
#pragma unroll
        for (int mi = 0; mi < 4; ++mi)
#pragma unroll
            for (int ks = 0; ks < 2; ++ks) {
                int r = 16 * (4 + mi) + llo;
                a[mi][ks] = ds_read_b128_o(&As[buf][wr][r][((ks * 4 + lhi) ^ (llo & 7)) << 3]);
            }

        asm volatile("s_waitcnt lgkmcnt(0)" ::: "memory");
        __builtin_amdgcn_sched_barrier(0);
        __builtin_amdgcn_s_setprio(1);
#pragma unroll
        for (int ks = 0; ks < 2; ++ks)
#pragma unroll
            for (int mi = 0; mi < 4; ++mi)
#pragma unroll
                for (int ni = 0; ni < 2; ++ni)
                    acc[4 + mi][2 + ni] = __builtin_amdgcn_mfma_f32_16x16x32_bf16(
                        a[mi][ks], b1[ni][ks], acc[4 + mi][2 + ni], 0, 0, 0);
        __builtin_amdgcn_s_setprio(0);

        __builtin_amdgcn_s_barrier();   // #2

        if (kt + 2 < NT) { stageA(kt + 2, 0); stageA(kt + 2, 1); }
        __builtin_amdgcn_s_setprio(1);
#pragma unroll
        for (int ks = 0; ks < 2; ++ks)
#pragma unroll
            for (int mi = 0; mi < 4; ++mi)
#pragma unroll
                for (int ni = 0; ni < 2; ++ni)
                    acc[4 + mi][ni] = __builtin_amdgcn_mfma_f32_16x16x32_bf16(
                        a[mi][ks], b0[ni][ks], acc[4 + mi][ni], 0, 0, 0);
        __builtin_amdgcn_s_setprio(0);

        if (kt + 2 < NT)      { asm volatile("s_waitcnt vmcnt(8)" ::: "memory"); }
        else if (kt + 1 < NT) { asm volatile("s_waitcnt vmcnt(0)" ::: "memory"); }
        __builtin_amdgcn_s_barrier();   // #3
    }

    int rbase = 128 * wr;
    int cbase = 64 * wc;
#pragma unroll
    for (int ni = 0; ni < 4; ++ni) {
#pragma unroll
        for (int mi = 0; mi < 8; ++mi)
#pragma unroll
            for (int rr = 0; rr < 4; ++rr) {
                int gr = rbase + 16 * mi + 4 * lhi + rr;
                out[(size_t)gr * DM + cbase + 16 * ni + llo] = f2bf(acc[mi][ni][rr]);
            }
    }
}

// -------- table-driven rotary + per-head LN (one block per token row) ---------
__global__ __launch_bounds__(256)
void rot_ln_kernel(const u16* __restrict__ Qf, const u16* __restrict__ Kf,
                   const float* __restrict__ ftab,
                   const float* __restrict__ g, const float* __restrict__ b,
                   u16* __restrict__ qnB, u16* __restrict__ knB,
                   float qk_scale, float fold_q)
{
    int c = blockIdx.x, t = threadIdx.x;
    int h  = t >> 4;
    int dl = (t & 15) * 8;
    const float* tab = ftab + ((size_t)c * 64 + (dl >> 1)) * 2;
    float fre[4], fim[4];
#pragma unroll
    for (int p = 0; p < 4; ++p) { fre[p] = tab[2 * p]; fim[p] = tab[2 * p + 1]; }
    float gv[8], bv2[8];
#pragma unroll
    for (int j = 0; j < 8; ++j) { gv[j] = g[dl + j]; bv2[j] = b[dl + j]; }

#pragma unroll
    for (int z = 0; z < 2; ++z) {
        const u16* src = z ? Kf : Qf;
        u16* dst = z ? knB : qnB;
        float fold = z ? 1.f : fold_q;
        short8 vv = *(const short8*)(src + (size_t)c * DM + t * 8);
        float o[8];
        float s = 0.f, ss = 0.f;
#pragma unroll
        for (int p = 0; p < 4; ++p) {
            float a  = bf2f((u16)vv[2 * p])     * qk_scale;
            float b2 = bf2f((u16)vv[2 * p + 1]) * qk_scale;
            float o0 = a * fre[p] - b2 * fim[p];
            float o1 = a * fim[p] + b2 * fre[p];
            o[2 * p] = o0; o[2 * p + 1] = o1;
            s += o0 + o1;
            ss += o0 * o0 + o1 * o1;
        }
#pragma unroll
        for (int off = 1; off < 16; off <<= 1) {
            s += __shfl_xor(s, off);
            ss += __shfl_xor(ss, off);
        }
        float mu   = s * (1.f / HD);
        float var  = ss * (1.f / HD) - mu * mu;
        float rstd = rsqrtf(var + 1e-5f);
        short8 r;
#pragma unroll
        for (int j = 0; j < 8; ++j)
            r[j] = (short)f2bf(((o[j] - mu) * rstd * gv[j] + bv2[j]) * fold);
        *(short8*)(dst + ((size_t)h * CTX + c) * HD + dl) = r;
    }
}

// ---------------- causal flash attention v4b ----------------------------------
__global__ __launch_bounds__(256, 2)
void attn_kernel(const u16* __restrict__ qn, const u16* __restrict__ kn,
                 const u16* __restrict__ vT, u16* __restrict__ aout)
{
    __shared__ __align__(16) u16 Kb[2][64][128];
    __shared__ __align__(16) u16 Vb[2][128][64];
    __shared__ __align__(16) u16 p_lds[4][16][72];

    int h  = blockIdx.y;
    int xs = blockIdx.x;
    int qb = (h >= 8) ? (31 - xs) : xs;   // CU load-balance pairing
    int q0 = qb * 64;
    int tid = threadIdx.x, w = tid >> 6, l = tid & 63;
    int lhi = l >> 4, llo = l & 15;

    const u16* qrow = qn + ((size_t)h * CTX + q0 + 16 * w + llo) * HD + 8 * lhi;
    short8 qf[4];
#pragma unroll
    for (int ks = 0; ks < 4; ++ks) qf[ks] = *(const short8*)(qrow + 32 * ks);

    auto stage = [&](int buf, int kv0) {
        int rb = 16 * w;
#pragma unroll
        for (int j = 0; j < 4; ++j) {
            int r = rb + 4 * j + (l >> 4);
            int csw = (l & 15) ^ (r & 15);
            const u16* src = kn + ((size_t)h * CTX + kv0 + r) * HD + (csw << 3);
            __builtin_amdgcn_global_load_lds((const __attribute__((address_space(1))) void*)src,
                (__attribute__((address_space(3))) void*)&Kb[buf][rb + 4 * j][0], 16, 0, 0);
        }
        int db = 32 * w;
#pragma unroll
        for (int j = 0; j < 4; ++j) {
            int d = db + 8 * j + (l >> 3);
            int csw = (l & 7) ^ (d & 7);
            const u16* src = vT + ((size_t)h * HD + d) * CTX + kv0 + (csw << 3);
            __builtin_amdgcn_global_load_lds((const __attribute__((address_space(1))) void*)src,
                (__attribute__((address_space(3))) void*)&Vb[buf][db + 8 * j][0], 16, 0, 0);
        }
    };

    float m_s = -1e30f, l_p = 0.f;
    f32x4 o_acc[8];
#pragma unroll
    for (int ni = 0; ni < 8; ++ni) o_acc[ni] = (f32x4){0.f, 0.f, 0.f, 0.f};

    stage(0, 0);
    __syncthreads();

    int cur = 0;
    for (int jt = 0; jt <= qb; ++jt) {
        if (jt < qb) stage(cur ^ 1, (jt + 1) * 64);   // prefetch overlaps compute

        f32x4 sacc[4] = {};
        __builtin_amdgcn_s_setprio(1);
#pragma unroll
        for (int ks = 0; ks < 4; ++ks) {
#pragma unroll
            for (int ni = 0; ni < 4; ++ni) {
                short8 kf = *(const short8*)&Kb[cur][16 * ni + llo][((4 * ks + lhi) ^ llo) << 3];
                sacc[ni] = __builtin_amdgcn_mfma_f32_16x16x32_bf16(kf, qf[ks], sacc[ni], 0, 0, 0);
            }
        }
        __builtin_amdgcn_s_setprio(0);

        if (jt == qb) {                  // causal mask inside diagonal tile
            int qloc = 16 * w + llo;
#pragma unroll
            for (int ni = 0; ni < 4; ++ni)
#pragma unroll
                for (int r = 0; r < 4; ++r)
                    if (16 * ni + 4 * lhi + r > qloc) sacc[ni][r] = -INFINITY;
        }

        // speculative P with OLD running max (no cross-lane wait)
        float pv[16];
#pragma unroll
        for (int ni = 0; ni < 4; ++ni)
#pragma unroll
            for (int r = 0; r < 4; ++r) pv[4 * ni + r] = exp2f(sacc[ni][r] - m_s);

        // per-lane local max only; __any supplies the cross-lane OR
        float mx = sacc[0][0];
#pragma unroll
        for (int ni = 0; ni < 4; ++ni)
#pragma unroll
            for (int r = 0; r < 4; ++r) mx = fmaxf(mx, sacc[ni][r]);

        if (__any(mx > m_s + 8.f)) {     // rare path: full reduce + rescale
            mx = fmaxf(mx, __shfl_xor(mx, 16));
            mx = fmaxf(mx, __shfl_xor(mx, 32));
            float mnew = fmaxf(m_s, mx);
            float fac = exp2f(m_s - mnew);
#pragma unroll
            for (int r = 0; r < 4; ++r) {
                float fr = __shfl(fac, 4 * lhi + r);
#pragma unroll
                for (int ni = 0; ni < 8; ++ni) o_acc[ni][r] *= fr;
            }
#pragma unroll
            for (int ni = 0; ni < 4; ++ni)
#pragma unroll
                for (int r = 0; r < 4; ++r) pv[4 * ni + r] = exp2f(sacc[ni][r] - mnew);
            l_p *= fac;
            m_s = mnew;
        }

        // pack P -> p_lds
#pragma unroll
        for (int ni = 0; ni < 4; ++ni)
#pragma unroll
            for (int hf = 0; hf < 2; ++hf) {
                unsigned pk;
                asm("v_cvt_pk_bf16_f32 %0, %1, %2" : "=v"(pk)
                    : "v"(pv[4 * ni + 2 * hf]), "v"(pv[4 * ni + 2 * hf + 1]));
                *(unsigned*)&p_lds[w][llo][16 * ni + 4 * lhi + 2 * hf] = pk;
            }

        // deferred l: per-lane partial only (cross-lane reduce in epilogue)
        float ps = 0.f;
#pragma unroll
        for (int j = 0; j < 16; ++j) ps += pv[j];
        l_p += ps;

        // O += P . V
        __builtin_amdgcn_s_setprio(1);
#pragma unroll
        for (int ks = 0; ks < 2; ++ks) {
            short8 pa = *(const short8*)&p_lds[w][llo][32 * ks + 8 * lhi];
#pragma unroll
            for (int ni = 0; ni < 8; ++ni) {
                short8 vf = *(const short8*)&Vb[cur][16 * ni + llo][((4 * ks + lhi) ^ (llo & 7)) << 3];
                o_acc[ni] = __builtin_amdgcn_mfma_f32_16x16x32_bf16(pa, vf, o_acc[ni], 0, 0, 0);
            }
        }
        __builtin_amdgcn_s_setprio(0);

        __syncthreads();   // drains prefetch vmcnt + frees buf[cur]
        cur ^= 1;
    }

    float lsum = l_p;
    lsum += __shfl_xor(lsum, 16);
    lsum += __shfl_xor(lsum, 32);
#pragma unroll
    for (int r = 0; r < 4; ++r) {
        float lr  = __shfl(lsum, 4 * lhi + r);
        float inv = 1.f / lr;
        int qrow2 = q0 + 16 * w + 4 * lhi + r;
#pragma unroll
        for (int ni = 0; ni < 8; ++ni)
            aout[(size_t)qrow2 * DM + h * HD + 16 * ni + llo] = f2bf(o_acc[ni][r] * inv);
    }
}

// ---------------- combine 4 bf16 split-K partials + bias ----------------------
__global__ __launch_bounds__(256)
void combine4_kernel(const u16* __restrict__ p, const float* __restrict__ bias,
                     float* __restrict__ out)
{
    size_t i = ((size_t)blockIdx.x * 256 + threadIdx.x) * 8;
    short8 a0 = *(const short8*)(p + i);
    short8 a1 = *(const short8*)(p + (size_t)CTX * DM + i);
    short8 a2 = *(const short8*)(p + 2 * (size_t)CTX * DM + i);
    short8 a3 = *(const short8*)(p + 3 * (size_t)CTX * DM + i);
    int dbase = (int)(i & (DM - 1));
    float4 bv0 = *(const float4*)(bias + dbase);
    float4 bv1 = *(const float4*)(bias + dbase + 4);
    float r[8];
    float bvv[8] = {bv0.x, bv0.y, bv0.z, bv0.w, bv1.x, bv1.y, bv1.z, bv1.w};
#pragma unroll
    for (int j = 0; j < 8; ++j)
        r[j] = (bf2f((u16)a0[j]) + bf2f((u16)a1[j]))
             + (bf2f((u16)a2[j]) + bf2f((u16)a3[j])) + bvv[j];
    *(float4*)(out + i)     = (float4){r[0], r[1], r[2], r[3]};
    *(float4*)(out + i + 4) = (float4){r[4], r[5], r[6], r[7]};
}

// ------------------------------- launcher ------------------------------------
extern "C" void kernel_launch(void* const* d_in, const int* in_sizes, int n_in,
                              void* d_out, int out_size, void* d_ws, size_t ws_size,
                              hipStream_t stream)
{
    const float* x   = (const float*)d_in[0];
    const float* qng = (const float*)d_in[1];
    const float* qnb = (const float*)d_in[2];
    const float* kng = (const float*)d_in[3];
    const float* knb = (const float*)d_in[4];
    const float* Wq  = (const float*)d_in[5];
    const float* bq  = (const float*)d_in[6];
    const float* Wkv = (const float*)d_in[7];
    const float* bkv = (const float*)d_in[8];
    const float* Wo  = (const float*)d_in[9];
    const float* bo  = (const float*)d_in[10];
    const float* lng = (const float*)d_in[11];
    const float* lnb = (const float*)d_in[12];
    float* out = (float*)d_out;

    uint8_t* ws = (uint8_t*)d_ws;
    size_t off = 0;
    auto alloc = [&](size_t bytes) -> void* {
        void* p = ws + off;
        off += (bytes + 255) & ~(size_t)255;
        return p;
    };
    u16*   WqT  = (u16*)alloc((size_t)DM * DM * 2);
    u16*   WkvT = (u16*)alloc((size_t)2 * DM * DM * 2);
    u16*   WoT  = (u16*)alloc((size_t)DM * DM * 2);
    u16*   Aq   = (u16*)alloc((size_t)CTX * DM * 2);
    u16*   Akv  = (u16*)alloc((size_t)CTX * DM * 2);
    float* ftab = (float*)alloc((size_t)CTX * 64 * 2 * 4);
    u16*   Qf   = (u16*)alloc((size_t)CTX * DM * 2);
    u16*   Kf   = (u16*)alloc((size_t)CTX * DM * 2);
    u16*   vTB  = (u16*)alloc((size_t)CTX * DM * 2);
    u16*   qnB  = (u16*)alloc((size_t)CTX * DM * 2);
    u16*   knB  = (u16*)alloc((size_t)CTX * DM * 2);
    u16*   aB   = (u16*)alloc((size_t)CTX * DM * 2);
    u16*   oprt = (u16*)alloc((size_t)4 * CTX * DM * 2);
    (void)ws_size; (void)in_sizes; (void)n_in; (void)out_size;

    transpose_all_kernel<<<dim3(DM / 32, DM / 32, 4), dim3(32, 8), 0, stream>>>(
        Wq, Wo, Wkv, WqT, WoT, WkvT);

    ln_stats_kernel<<<CTX, 256, 0, stream>>>(x, qng, qnb, kng, knb, Aq, Akv, ftab);

    qkv_gemm256_kernel<<<dim3(384), 256, 0, stream>>>(
        Aq, Akv, WqT, WkvT, bq, bkv, Qf, Kf, vTB);

    const float qk_scale = 0.29730177875068026f;                       // 128^-0.25
    const float fold_q   = 0.08838834764831845f * 1.4426950408889634f; // 1/sqrt(128)*log2(e)
    rot_ln_kernel<<<CTX, 256, 0, stream>>>(
        Qf, Kf, ftab, lng, lnb, qnB, knB, qk_scale, fold_q);

    attn_kernel<<<dim3(CTX / 64, NH), 256, 0, stream>>>(qnB, knB, vTB, aB);

    oproj_gemm256_kernel<<<dim3(256), 512, 0, stream>>>(aB, WoT, oprt);
    combine4_kernel<<<(CTX * DM) / 2048, 256, 0, stream>>>(oprt, bo, out);
}

// Round 9
// 176.554 us; speedup vs baseline: 1.6289x; 1.6289x over previous
//
#include <hip/hip_runtime.h>
#include <stdint.h>
#include <math.h>

#define CTX 2048
#define DM  2048
#define NH  16
#define HD  128

typedef __attribute__((ext_vector_type(8))) short short8;   // 8 x bf16 (4 VGPRs)
typedef __attribute__((ext_vector_type(4))) float f32x4;    // MFMA acc
typedef unsigned short u16;

__device__ __forceinline__ u16 f2bf(float f) {
    unsigned u = __float_as_uint(f);
    unsigned r = u + 0x7fffu + ((u >> 16) & 1u);   // RTNE
    return (u16)(r >> 16);
}
__device__ __forceinline__ float bf2f(u16 h) {
    return __uint_as_float(((unsigned)h) << 16);
}

// Opaque LDS read: invisible to SIInsertWaitcnts' LDS-DMA alias tracking, so
// the compiler cannot insert vmcnt(0) drains before it. Ordering enforced
// manually: counted lgkmcnt + sched_barrier(0) before every consumer (rule #18).
__device__ __forceinline__ short8 ds_read_b128_o(const void* p) {
    short8 r;
    asm volatile("ds_read_b128 %0, %1"
                 : "=v"(r)
                 : "v"((const __attribute__((address_space(3))) void*)p));
    return r;
}

// ------- merged weight transpose + f32->bf16 (W[K][N] -> WT[N][K]), 4 slabs ---
__global__ __launch_bounds__(256)
void transpose_all_kernel(const float* __restrict__ Wq, const float* __restrict__ Wo,
                          const float* __restrict__ Wkv,
                          u16* __restrict__ WqT, u16* __restrict__ WoT, u16* __restrict__ WkvT)
{
    __shared__ float tile[32][33];
    int z = blockIdx.z;
    const float* S; u16* D; int nsrc, c0, r0;
    if (z == 0)      { S = Wq;  D = WqT;  nsrc = DM;     c0 = 0;  r0 = 0;    }
    else if (z == 1) { S = Wo;  D = WoT;  nsrc = DM;     c0 = 0;  r0 = 0;    }
    else if (z == 2) { S = Wkv; D = WkvT; nsrc = 2 * DM; c0 = 0;  r0 = 0;    }
    else             { S = Wkv; D = WkvT; nsrc = 2 * DM; c0 = DM; r0 = DM;   }
    int k0 = blockIdx.x * 32, n0 = blockIdx.y * 32;
    int tx = threadIdx.x, ty = threadIdx.y;          // 32 x 8
#pragma unroll
    for (int j = 0; j < 4; ++j) {
        int kk = ty + 8 * j;
        tile[kk][tx] = S[(size_t)(k0 + kk) * nsrc + c0 + n0 + tx];
    }
    __syncthreads();
#pragma unroll
    for (int j = 0; j < 4; ++j) {
        int nn = ty + 8 * j;
        D[(size_t)(r0 + n0 + nn) * DM + k0 + tx] = f2bf(tile[tx][nn]);
    }
}

// -------- LN stats + normalized A matrices (bf16) + rotary factor table -------
__global__ __launch_bounds__(256)
void ln_stats_kernel(const float* __restrict__ x,
                     const float* __restrict__ qg, const float* __restrict__ qb,
                     const float* __restrict__ kg, const float* __restrict__ kb,
                     u16* __restrict__ Aq, u16* __restrict__ Akv, float* __restrict__ ftab)
{
    int c = blockIdx.x, t = threadIdx.x;
    const float* row = x + (size_t)c * DM;
    float4 v0 = *(const float4*)(row + t * 8);
    float4 v1 = *(const float4*)(row + t * 8 + 4);
    float vals[8] = {v0.x, v0.y, v0.z, v0.w, v1.x, v1.y, v1.z, v1.w};
    float s = 0.f, ss = 0.f;
#pragma unroll
    for (int j = 0; j < 8; ++j) { s += vals[j]; ss += vals[j] * vals[j]; }
#pragma unroll
    for (int off = 32; off; off >>= 1) { s += __shfl_xor(s, off); ss += __shfl_xor(ss, off); }
    __shared__ float red[8];
    int w = t >> 6;
    if ((t & 63) == 0) { red[w] = s; red[4 + w] = ss; }
    __syncthreads();
    float st  = red[0] + red[1] + red[2] + red[3];
    float sst = red[4] + red[5] + red[6] + red[7];
    float mu   = st * (1.f / DM);
    float var  = sst * (1.f / DM) - mu * mu;
    float rstd = rsqrtf(var + 1e-5f);
    if (t < 64) {                         // rotary table, m folded in
        const float LT64 = 10.30895266f / 64.f;   // ln(30000)/64
        float m = sqrtf(sst);
        float sn, cs;
        sincosf((float)c * ((float)t * LT64), &sn, &cs);
        float2 wv = {m * cs, m * sn};
        *(float2*)(ftab + ((size_t)c * 64 + t) * 2) = wv;
    }
    short8 aq, akv;
#pragma unroll
    for (int j = 0; j < 8; ++j) {
        int d = t * 8 + j;
        float xh = (vals[j] - mu) * rstd;
        aq[j]  = (short)f2bf(xh * qg[d] + qb[d]);
        akv[j] = (short)f2bf(xh * kg[d] + kb[d]);
    }
    *(short8*)(Aq  + (size_t)c * DM + t * 8) = aq;
    *(short8*)(Akv + (size_t)c * DM + t * 8) = akv;
}

// ---------------- fused QKV projection GEMM -----------------------------------
// v5 (REVERTED from v6's global->reg B gather, which was uncoalesced: lanes at
// llo*DM stride = 4KB apart -> 64 cache lines per load, FETCH 52->90MB, 162us).
// 128x256 tile, BK=64, 4 waves (1Mx4N), SINGLE-buffered 48 KiB LDS ->
// 2 blocks/CU co-resident, grid 384 = all 256 CUs busy. Cross-block TLP covers
// the stage stall and lgkm drains. Proven 61us / passing (round 6).
__global__ __launch_bounds__(256, 2)
void qkv_gemm256_kernel(const u16* __restrict__ Aq, const u16* __restrict__ Akv,
                        const u16* __restrict__ WqT, const u16* __restrict__ WkvT,
                        const float* __restrict__ bq, const float* __restrict__ bkv,
                        u16* __restrict__ Qf, u16* __restrict__ Kf, u16* __restrict__ vT)
{
    __shared__ __align__(16) u16 As[128][64];         // 16 KiB
    __shared__ __align__(16) u16 Bs[2][128][64];      // 32 KiB

    constexpr int NT = DM / 64;                       // 32 K-tiles

    // XCD swizzle: 384 blocks, 48 contiguous per XCD (384 % 8 == 0, bijective).
    int lin = blockIdx.x;
    int swz = (lin & 7) * 48 + (lin >> 3);
    int mt  = swz & 15;         // M tile 0..15 (128 rows)
    int ng  = swz >> 4;         // 0..23
    int seg = ng >> 3;          // 0:Q 1:K 2:V
    int nt  = ng & 7;           // N tile 0..7 (256 cols)

    const u16* Amat; const u16* Bmat; const float* bias; u16* outp; bool rowbias;
    if (seg == 0) {
        Amat = Aq  + (size_t)mt * 128 * DM;
        Bmat = WqT + (size_t)nt * 256 * DM;
        bias = bq + nt * 256;
        outp = Qf + (size_t)mt * 128 * DM + nt * 256;
        rowbias = false;
    } else if (seg == 1) {
        Amat = Akv  + (size_t)mt * 128 * DM;
        Bmat = WkvT + (size_t)nt * 256 * DM;
        bias = bkv + nt * 256;
        outp = Kf + (size_t)mt * 128 * DM + nt * 256;
        rowbias = false;
    } else {
        Amat = WkvT + (size_t)(DM + mt * 128) * DM;   // V dims as GEMM rows
        Bmat = Akv  + (size_t)nt * 256 * DM;          // context as GEMM cols
        bias = bkv + DM + mt * 128;                   // per-row bias
        outp = vT + (size_t)mt * 128 * CTX + nt * 256;
        rowbias = true;
    }

    int tid = threadIdx.x;
    int wid = tid >> 6, l = tid & 63;                 // 4 waves, wave = N slice
    int wc = wid;                                     // 0..3
    int lhi = l >> 4, llo = l & 15;
    int srow  = l >> 3;                               // staging row within 8-row group
    int sunit = (l & 7) ^ srow;                       // inverse-swizzled 16B unit

    // stage tile kt: A 128x64 (4 loads/wave), B 2x128x64 (8 loads/wave)
    auto stage = [&](int kt) {
#pragma unroll
        for (int rd = 0; rd < 4; ++rd) {
            int r = wid * 32 + rd * 8;
            const u16* src = Amat + (size_t)(r + srow) * DM + kt * 64 + sunit * 8;
            __builtin_amdgcn_global_load_lds((const __attribute__((address_space(1))) void*)src,
                (__attribute__((address_space(3))) void*)&As[r][0], 16, 0, 0);
        }
#pragma unroll
        for (int h = 0; h < 2; ++h)
#pragma unroll
            for (int rd = 0; rd < 4; ++rd) {
                int r = wid * 32 + rd * 8;
                const u16* src = Bmat + (size_t)(h * 128 + r + srow) * DM + kt * 64 + sunit * 8;
                __builtin_amdgcn_global_load_lds((const __attribute__((address_space(1))) void*)src,
                    (__attribute__((address_space(3))) void*)&Bs[h][r][0], 16, 0, 0);
            }
    };

    f32x4 acc[8][4] = {};                 // accumulator
    short8 a[4][2];                       // reused for a03 then a47 (VGPR cap)
    short8 b0[2][2], b1[2][2];
    int bhalf = wc >> 1, brow = (wc & 1) * 64;

    stage(0);
    asm volatile("s_waitcnt vmcnt(0)" ::: "memory");
    __builtin_amdgcn_s_barrier();

    for (int kt = 0; kt < NT; ++kt) {
        // ---- reads: b0 (4) + a03 (8) + b1 (4) -------------------------------
#pragma unroll
        for (int ni = 0; ni < 2; ++ni)
#pragma unroll
            for (int ks = 0; ks < 2; ++ks) {
                int r = brow + 16 * ni + llo;
                b0[ni][ks] = ds_read_b128_o(&Bs[bhalf][r][((ks * 4 + lhi) ^ (llo & 7)) << 3]);
            }
#pragma unroll
        for (int mi = 0; mi < 4; ++mi)
#pragma unroll
            for (int ks = 0; ks < 2; ++ks) {
                int r = 16 * mi + llo;
                a[mi][ks] = ds_read_b128_o(&As[r][((ks * 4 + lhi) ^ (llo & 7)) << 3]);
            }
#pragma unroll
        for (int ni = 0; ni < 2; ++ni)
#pragma unroll
            for (int ks = 0; ks < 2; ++ks) {
                int r = brow + 16 * (2 + ni) + llo;
                b1[ni][ks] = ds_read_b128_o(&Bs[bhalf][r][((ks * 4 + lhi) ^ (llo & 7)) << 3]);
            }

        // ---- q00 ------------------------------------------------------------
        asm volatile("s_waitcnt lgkmcnt(4)" ::: "memory");
        __builtin_amdgcn_sched_barrier(0);
        __builtin_amdgcn_s_setprio(1);
#pragma unroll
        for (int ks = 0; ks < 2; ++ks)
#pragma unroll
            for (int mi = 0; mi < 4; ++mi)
#pragma unroll
                for (int ni = 0; ni < 2; ++ni)
                    acc[mi][ni] = __builtin_amdgcn_mfma_f32_16x16x32_bf16(
                        a[mi][ks], b0[ni][ks], acc[mi][ni], 0, 0, 0);
        __builtin_amdgcn_s_setprio(0);

        // ---- q01 ------------------------------------------------------------
        asm volatile("s_waitcnt lgkmcnt(0)" ::: "memory");
        __builtin_amdgcn_sched_barrier(0);
        __builtin_amdgcn_s_setprio(1);
#pragma unroll
        for (int ks = 0; ks < 2; ++ks)
#pragma unroll
            for (int mi = 0; mi < 4; ++mi)
#pragma unroll
                for (int ni = 0; ni < 2; ++ni)
                    acc[mi][2 + ni] = __builtin_amdgcn_mfma_f32_16x16x32_bf16(
                        a[mi][ks], b1[ni][ks], acc[mi][2 + ni], 0, 0, 0);
        __builtin_amdgcn_s_setprio(0);

        // ---- read a47 (reuse regs); q11, q10 --------------------------------
#pragma unroll
        for (int mi = 0; mi < 4; ++mi)
#pragma unroll
            for (int ks = 0; ks < 2; ++ks) {
                int r = 16 * (4 + mi) + llo;
                a[mi][ks] = ds_read_b128_o(&As[r][((ks * 4 + lhi) ^ (llo & 7)) << 3]);
            }
        asm volatile("s_waitcnt lgkmcnt(0)" ::: "memory");
        __builtin_amdgcn_sched_barrier(0);
        __builtin_amdgcn_s_setprio(1);
#pragma unroll
        for (int ks = 0; ks < 2; ++ks)
#pragma unroll
            for (int mi = 0; mi < 4; ++mi)
#pragma unroll
                for (int ni = 0; ni < 2; ++ni)
                    acc[4 + mi][2 + ni] = __builtin_amdgcn_mfma_f32_16x16x32_bf16(
                        a[mi][ks], b1[ni][ks], acc[4 + mi][2 + ni], 0, 0, 0);
#pragma unroll
        for (int ks = 0; ks < 2; ++ks)
#pragma unroll
            for (int mi = 0; mi < 4; ++mi)
#pragma unroll
                for (int ni = 0; ni < 2; ++ni)
                    acc[4 + mi][ni] = __builtin_amdgcn_mfma_f32_16x16x32_bf16(
                        a[mi][ks], b0[ni][ks], acc[4 + mi][ni], 0, 0, 0);
        __builtin_amdgcn_s_setprio(0);

        // ---- all reads of S retired block-wide -> restage -------------------
        __builtin_amdgcn_s_barrier();
        if (kt + 1 < NT) {
            stage(kt + 1);
            asm volatile("s_waitcnt vmcnt(0)" ::: "memory");
            __builtin_amdgcn_s_barrier();
        }
    }

    // ---------------- epilogue: bias + bf16 store ----------------------------
    int cbase = 64 * wc;
    if (!rowbias) {
#pragma unroll
        for (int ni = 0; ni < 4; ++ni) {
            float bv = bias[cbase + 16 * ni + llo];
#pragma unroll
            for (int mi = 0; mi < 8; ++mi)
#pragma unroll
                for (int rr = 0; rr < 4; ++rr) {
                    int gr = 16 * mi + 4 * lhi + rr;
                    outp[(size_t)gr * DM + cbase + 16 * ni + llo] = f2bf(acc[mi][ni][rr] + bv);
                }
        }
    } else {
#pragma unroll
        for (int mi = 0; mi < 8; ++mi)
#pragma unroll
            for (int rr = 0; rr < 4; ++rr) {
                int gr = 16 * mi + 4 * lhi + rr;
                float bv = bias[gr];
#pragma unroll
                for (int ni = 0; ni < 4; ++ni)
                    outp[(size_t)gr * CTX + cbase + 16 * ni + llo] = f2bf(acc[mi][ni][rr] + bv);
            }
    }
}

// ---------------- O-projection GEMM: 256^2 tile, 4-way split-K ----------------
__global__ __launch_bounds__(512, 2)
void oproj_gemm256_kernel(const u16* __restrict__ A, const u16* __restrict__ BT,
                          u16* __restrict__ outp)
{
    __shared__ __align__(16) u16 As[2][2][128][64];
    __shared__ __align__(16) u16 Bs[2][2][128][64];

    constexpr int NT = 8;                             // 8 K-tiles = 512 deep

    // XCD swizzle: 256 blocks, 32 contiguous per XCD (256 % 8 == 0, bijective)
    int lin = blockIdx.x;
    int swz = (lin & 7) * 32 + (lin >> 3);
    int kz  = swz >> 6;          // K split 0..3
    int rem = swz & 63;
    int mt  = rem & 7;
    int nt  = rem >> 3;

    const u16* Amat = A  + (size_t)mt * 256 * DM + kz * 512;
    const u16* Bmat = BT + (size_t)nt * 256 * DM + kz * 512;
    u16* out = outp + (size_t)kz * CTX * DM + (size_t)mt * 256 * DM + nt * 256;

    int tid = threadIdx.x;
    int wid = tid >> 6, l = tid & 63;
    int wr = wid >> 2, wc = wid & 3;
    int lhi = l >> 4, llo = l & 15;
    int srow  = l >> 3;
    int sunit = (l & 7) ^ srow;

    auto stageA = [&](int kt, int h) {
#pragma unroll
        for (int rd = 0; rd < 2; ++rd) {
            const u16* src = Amat + (size_t)(h * 128 + rd * 64 + wid * 8 + srow) * DM
                             + kt * 64 + sunit * 8;
            __builtin_amdgcn_global_load_lds((const __attribute__((address_space(1))) void*)src,
                (__attribute__((address_space(3))) void*)&As[kt & 1][h][rd * 64 + wid * 8][0],
                16, 0, 0);
        }
    };
    auto stageB = [&](int kt, int h) {
#pragma unroll
        for (int rd = 0; rd < 2; ++rd) {
            const u16* src = Bmat + (size_t)(h * 128 + rd * 64 + wid * 8 + srow) * DM
                             + kt * 64 + sunit * 8;
            __builtin_amdgcn_global_load_lds((const __attribute__((address_space(1))) void*)src,
                (__attribute__((address_space(3))) void*)&Bs[kt & 1][h][rd * 64 + wid * 8][0],
                16, 0, 0);
        }
    };

    f32x4 acc[8][4] = {};
    short8 a[4][2];
    short8 b0[2][2], b1[2][2];
    int bhalf = wc >> 1, brow = (wc & 1) * 64;

    stageA(0, 0); stageA(0, 1); stageB(0, 0); stageB(0, 1);
    stageA(1, 0); stageA(1, 1); stageB(1, 0); stageB(1, 1);
    asm volatile("s_waitcnt vmcnt(8)" ::: "memory");
    __builtin_amdgcn_s_barrier();

    for (int kt = 0; kt < NT; ++kt) {
        int buf = kt & 1;

#pragma unroll
        for (int ni = 0; ni < 2; ++ni)
#pragma unroll
            for (int ks = 0; ks < 2; ++ks) {
                int r = brow + 16 * ni + llo;
                b0[ni][ks] = ds_read_b128_o(&Bs[buf][bhalf][r][((ks * 4 + lhi) ^ (llo & 7)) << 3]);
            }
#pragma unroll
        for (int mi = 0; mi < 4; ++mi)
#pragma unroll
            for (int ks = 0; ks < 2; ++ks) {
                int r = 16 * mi + llo;
                a[mi][ks] = ds_read_b128_o(&As[buf][wr][r][((ks * 4 + lhi) ^ (llo & 7)) << 3]);
            }
#pragma unroll
        for (int ni = 0; ni < 2; ++ni)
#pragma unroll
            for (int ks = 0; ks < 2; ++ks) {
                int r = brow + 16 * (2 + ni) + llo;
                b1[ni][ks] = ds_read_b128_o(&Bs[buf][bhalf][r][((ks * 4 + lhi) ^ (llo & 7)) << 3]);
            }

        asm volatile("s_waitcnt lgkmcnt(4)" ::: "memory");
        __builtin_amdgcn_sched_barrier(0);
        __builtin_amdgcn_s_setprio(1);
#pragma unroll
        for (int ks = 0; ks < 2; ++ks)
#pragma unroll
            for (int mi = 0; mi < 4; ++mi)
#pragma unroll
                for (int ni = 0; ni < 2; ++ni)
                    acc[mi][ni] = __builtin_amdgcn_mfma_f32_16x16x32_bf16(
                        a[mi][ks], b0[ni][ks], acc[mi][ni], 0, 0, 0);
        __builtin_amdgcn_s_setprio(0);

        asm volatile("s_waitcnt lgkmcnt(0)" ::: "memory");
        __builtin_amdgcn_sched_barrier(0);
        __builtin_amdgcn_s_setprio(1);
#pragma unroll
        for (int ks = 0; ks < 2; ++ks)
#pragma unroll
            for (int mi = 0; mi < 4; ++mi)
#pragma unroll
                for (int ni = 0; ni < 2; ++ni)
                    acc[mi][2 + ni] = __builtin_amdgcn_mfma_f32_16x16x32_bf16(
                        a[mi][ks], b1[ni][ks], acc[mi][2 + ni], 0, 0, 0);
        __builtin_amdgcn_s_setprio(0);

        __builtin_amdgcn_s_barrier();   // #1

        if (kt + 2 < NT) { stageB(kt + 2, 0); stageB(kt + 2, 1); }
#pragma unroll
        for (int mi = 0; mi < 4; ++mi)
#pragma unroll
            for (int ks = 0; ks < 2; ++ks) {
                int r = 16 * (4 + mi) + llo;
                a[mi][ks] = ds_read_b128_o(&As[buf][wr][r][((ks * 4 + lhi) ^ (llo & 7)) << 3]);
            }

        asm volatile("s_waitcnt lgkmcnt(0)" ::: "memory");
        __builtin_amdgcn_sched_barrier(0);
        __builtin_amdgcn_s_setprio(1);
#pragma unroll
        for (int ks = 0; ks < 2; ++ks)
#pragma unroll
            for (int mi = 0; mi < 4; ++mi)
#pragma unroll
                for (int ni = 0; ni < 2; ++ni)
                    acc[4 + mi][2 + ni] = __builtin_amdgcn_mfma_f32_16x16x32_bf16(
                        a[mi][ks], b1[ni][ks], acc[4 + mi][2 + ni], 0, 0, 0);
        __builtin_amdgcn_s_setprio(0);

        __builtin_amdgcn_s_barrier();   // #2

        if (kt + 2 < NT) { stageA(kt + 2, 0); stageA(kt + 2, 1); }
        __builtin_amdgcn_s_setprio(1);
#pragma unroll
        for (int ks = 0; ks < 2; ++ks)
#pragma unroll
            for (int mi = 0; mi < 4; ++mi)
#pragma unroll
                for (int ni = 0; ni < 2; ++ni)
                    acc[4 + mi][ni] = __builtin_amdgcn_mfma_f32_16x16x32_bf16(
                        a[mi][ks], b0[ni][ks], acc[4 + mi][ni], 0, 0, 0);
        __builtin_amdgcn_s_setprio(0);

        if (kt + 2 < NT)      { asm volatile("s_waitcnt vmcnt(8)" ::: "memory"); }
        else if (kt + 1 < NT) { asm volatile("s_waitcnt vmcnt(0)" ::: "memory"); }
        __builtin_amdgcn_s_barrier();   // #3
    }

    int rbase = 128 * wr;
    int cbase = 64 * wc;
#pragma unroll
    for (int ni = 0; ni < 4; ++ni) {
#pragma unroll
        for (int mi = 0; mi < 8; ++mi)
#pragma unroll
            for (int rr = 0; rr < 4; ++rr) {
                int gr = rbase + 16 * mi + 4 * lhi + rr;
                out[(size_t)gr * DM + cbase + 16 * ni + llo] = f2bf(acc[mi][ni][rr]);
            }
    }
}

// -------- table-driven rotary + per-head LN (one block per token row) ---------
__global__ __launch_bounds__(256)
void rot_ln_kernel(const u16* __restrict__ Qf, const u16* __restrict__ Kf,
                   const float* __restrict__ ftab,
                   const float* __restrict__ g, const float* __restrict__ b,
                   u16* __restrict__ qnB, u16* __restrict__ knB,
                   float qk_scale, float fold_q)
{
    int c = blockIdx.x, t = threadIdx.x;
    int h  = t >> 4;
    int dl = (t & 15) * 8;
    const float* tab = ftab + ((size_t)c * 64 + (dl >> 1)) * 2;
    float fre[4], fim[4];
#pragma unroll
    for (int p = 0; p < 4; ++p) { fre[p] = tab[2 * p]; fim[p] = tab[2 * p + 1]; }
    float gv[8], bv2[8];
#pragma unroll
    for (int j = 0; j < 8; ++j) { gv[j] = g[dl + j]; bv2[j] = b[dl + j]; }

#pragma unroll
    for (int z = 0; z < 2; ++z) {
        const u16* src = z ? Kf : Qf;
        u16* dst = z ? knB : qnB;
        float fold = z ? 1.f : fold_q;
        short8 vv = *(const short8*)(src + (size_t)c * DM + t * 8);
        float o[8];
        float s = 0.f, ss = 0.f;
#pragma unroll
        for (int p = 0; p < 4; ++p) {
            float a  = bf2f((u16)vv[2 * p])     * qk_scale;
            float b2 = bf2f((u16)vv[2 * p + 1]) * qk_scale;
            float o0 = a * fre[p] - b2 * fim[p];
            float o1 = a * fim[p] + b2 * fre[p];
            o[2 * p] = o0; o[2 * p + 1] = o1;
            s += o0 + o1;
            ss += o0 * o0 + o1 * o1;
        }
#pragma unroll
        for (int off = 1; off < 16; off <<= 1) {
            s += __shfl_xor(s, off);
            ss += __shfl_xor(ss, off);
        }
        float mu   = s * (1.f / HD);
        float var  = ss * (1.f / HD) - mu * mu;
        float rstd = rsqrtf(var + 1e-5f);
        short8 r;
#pragma unroll
        for (int j = 0; j < 8; ++j)
            r[j] = (short)f2bf(((o[j] - mu) * rstd * gv[j] + bv2[j]) * fold);
        *(short8*)(dst + ((size_t)h * CTX + c) * HD + dl) = r;
    }
}

// ---------------- causal flash attention v5 ------------------------------------
// v4b + opaque LDS reads. v4b had the round-1 qkv bug: global_load_lds prefetch
// + compiler-visible ds_reads -> SIInsertWaitcnts emits vmcnt(0) before the
// first K-fragment read, so tile jt's compute waited for tile jt+1's HBM loads
// (prefetch defeated). All Kb/Vb/p_lds reads are now opaque asm with explicit
// counted lgkmcnt + sched_barrier(0) (rule #18); the only vmcnt(0) left is in
// the end-of-iteration __syncthreads, which is exactly where tile jt+1 must
// have landed. QK^T pipelines two 4-fragment K banks so the LDS pipe stays
// busy under the MFMA clusters.
__global__ __launch_bounds__(256, 2)
void attn_kernel(const u16* __restrict__ qn, const u16* __restrict__ kn,
                 const u16* __restrict__ vT, u16* __restrict__ aout)
{
    __shared__ __align__(16) u16 Kb[2][64][128];
    __shared__ __align__(16) u16 Vb[2][128][64];
    __shared__ __align__(16) u16 p_lds[4][16][72];

    int h  = blockIdx.y;
    int xs = blockIdx.x;
    int qb = (h >= 8) ? (31 - xs) : xs;   // CU load-balance pairing
    int q0 = qb * 64;
    int tid = threadIdx.x, w = tid >> 6, l = tid & 63;
    int lhi = l >> 4, llo = l & 15;

    const u16* qrow = qn + ((size_t)h * CTX + q0 + 16 * w + llo) * HD + 8 * lhi;
    short8 qf[4];
#pragma unroll
    for (int ks = 0; ks < 4; ++ks) qf[ks] = *(const short8*)(qrow + 32 * ks);

    auto stage = [&](int buf, int kv0) {
        int rb = 16 * w;
#pragma unroll
        for (int j = 0; j < 4; ++j) {
            int r = rb + 4 * j + (l >> 4);
            int csw = (l & 15) ^ (r & 15);
            const u16* src = kn + ((size_t)h * CTX + kv0 + r) * HD + (csw << 3);
            __builtin_amdgcn_global_load_lds((const __attribute__((address_space(1))) void*)src,
                (__attribute__((address_space(3))) void*)&Kb[buf][rb + 4 * j][0], 16, 0, 0);
        }
        int db = 32 * w;
#pragma unroll
        for (int j = 0; j < 4; ++j) {
            int d = db + 8 * j + (l >> 3);
            int csw = (l & 7) ^ (d & 7);
            const u16* src = vT + ((size_t)h * HD + d) * CTX + kv0 + (csw << 3);
            __builtin_amdgcn_global_load_lds((const __attribute__((address_space(1))) void*)src,
                (__attribute__((address_space(3))) void*)&Vb[buf][db + 8 * j][0], 16, 0, 0);
        }
    };

    float m_s = -1e30f, l_p = 0.f;
    f32x4 o_acc[8];
#pragma unroll
    for (int ni = 0; ni < 8; ++ni) o_acc[ni] = (f32x4){0.f, 0.f, 0.f, 0.f};

    stage(0, 0);
    __syncthreads();

    int cur = 0;
    for (int jt = 0; jt <= qb; ++jt) {
        if (jt < qb) stage(cur ^ 1, (jt + 1) * 64);   // prefetch overlaps compute

        // ---- QK^T: opaque reads, 2 pipelined K banks ------------------------
        f32x4 sacc[4] = {};
        short8 kf0[4], kf1[4];
#pragma unroll
        for (int ni = 0; ni < 4; ++ni)
            kf0[ni] = ds_read_b128_o(&Kb[cur][16 * ni + llo][(lhi ^ llo) << 3]);
#pragma unroll
        for (int ni = 0; ni < 4; ++ni)
            kf1[ni] = ds_read_b128_o(&Kb[cur][16 * ni + llo][((4 + lhi) ^ llo) << 3]);

        asm volatile("s_waitcnt lgkmcnt(4)" ::: "memory");   // kf0 ready
        __builtin_amdgcn_sched_barrier(0);
        __builtin_amdgcn_s_setprio(1);
#pragma unroll
        for (int ni = 0; ni < 4; ++ni)
            sacc[ni] = __builtin_amdgcn_mfma_f32_16x16x32_bf16(kf0[ni], qf[0], sacc[ni], 0, 0, 0);
        __builtin_amdgcn_s_setprio(0);

#pragma unroll
        for (int ni = 0; ni < 4; ++ni)
            kf0[ni] = ds_read_b128_o(&Kb[cur][16 * ni + llo][((8 + lhi) ^ llo) << 3]);
        asm volatile("s_waitcnt lgkmcnt(4)" ::: "memory");   // kf1 ready
        __builtin_amdgcn_sched_barrier(0);
        __builtin_amdgcn_s_setprio(1);
#pragma unroll
        for (int ni = 0; ni < 4; ++ni)
            sacc[ni] = __builtin_amdgcn_mfma_f32_16x16x32_bf16(kf1[ni], qf[1], sacc[ni], 0, 0, 0);
        __builtin_amdgcn_s_setprio(0);

#pragma unroll
        for (int ni = 0; ni < 4; ++ni)
            kf1[ni] = ds_read_b128_o(&Kb[cur][16 * ni + llo][((12 + lhi) ^ llo) << 3]);
        asm volatile("s_waitcnt lgkmcnt(4)" ::: "memory");   // kf0 (ks=2) ready
        __builtin_amdgcn_sched_barrier(0);
        __builtin_amdgcn_s_setprio(1);
#pragma unroll
        for (int ni = 0; ni < 4; ++ni)
            sacc[ni] = __builtin_amdgcn_mfma_f32_16x16x32_bf16(kf0[ni], qf[2], sacc[ni], 0, 0, 0);
        __builtin_amdgcn_s_setprio(0);

        asm volatile("s_waitcnt lgkmcnt(0)" ::: "memory");   // kf1 (ks=3) ready
        __builtin_amdgcn_sched_barrier(0);
        __builtin_amdgcn_s_setprio(1);
#pragma unroll
        for (int ni = 0; ni < 4; ++ni)
            sacc[ni] = __builtin_amdgcn_mfma_f32_16x16x32_bf16(kf1[ni], qf[3], sacc[ni], 0, 0, 0);
        __builtin_amdgcn_s_setprio(0);

        if (jt == qb) {                  // causal mask inside diagonal tile
            int qloc = 16 * w + llo;
#pragma unroll
            for (int ni = 0; ni < 4; ++ni)
#pragma unroll
                for (int r = 0; r < 4; ++r)
                    if (16 * ni + 4 * lhi + r > qloc) sacc[ni][r] = -INFINITY;
        }

        // speculative P with OLD running max (no cross-lane wait)
        float pv[16];
#pragma unroll
        for (int ni = 0; ni < 4; ++ni)
#pragma unroll
            for (int r = 0; r < 4; ++r) pv[4 * ni + r] = exp2f(sacc[ni][r] - m_s);

        // per-lane local max only; __any supplies the cross-lane OR
        float mx = sacc[0][0];
#pragma unroll
        for (int ni = 0; ni < 4; ++ni)
#pragma unroll
            for (int r = 0; r < 4; ++r) mx = fmaxf(mx, sacc[ni][r]);

        if (__any(mx > m_s + 8.f)) {     // rare path: full reduce + rescale
            mx = fmaxf(mx, __shfl_xor(mx, 16));
            mx = fmaxf(mx, __shfl_xor(mx, 32));
            float mnew = fmaxf(m_s, mx);
            float fac = exp2f(m_s - mnew);
#pragma unroll
            for (int r = 0; r < 4; ++r) {
                float fr = __shfl(fac, 4 * lhi + r);
#pragma unroll
                for (int ni = 0; ni < 8; ++ni) o_acc[ni][r] *= fr;
            }
#pragma unroll
            for (int ni = 0; ni < 4; ++ni)
#pragma unroll
                for (int r = 0; r < 4; ++r) pv[4 * ni + r] = exp2f(sacc[ni][r] - mnew);
            l_p *= fac;
            m_s = mnew;
        }

        // pack P -> p_lds (wave-private region; DS pipe is in-order per wave)
#pragma unroll
        for (int ni = 0; ni < 4; ++ni)
#pragma unroll
            for (int hf = 0; hf < 2; ++hf) {
                unsigned pk;
                asm("v_cvt_pk_bf16_f32 %0, %1, %2" : "=v"(pk)
                    : "v"(pv[4 * ni + 2 * hf]), "v"(pv[4 * ni + 2 * hf + 1]));
                *(unsigned*)&p_lds[w][llo][16 * ni + 4 * lhi + 2 * hf] = pk;
            }

        // deferred l: per-lane partial only (cross-lane reduce in epilogue)
        float ps = 0.f;
#pragma unroll
        for (int j = 0; j < 16; ++j) ps += pv[j];
        l_p += ps;

        // pin pack-writes in program order before the opaque p_lds reads
        __builtin_amdgcn_sched_barrier(0);

        // ---- O += P . V (opaque reads + explicit waits) ---------------------
#pragma unroll
        for (int ks = 0; ks < 2; ++ks) {
            short8 pa = ds_read_b128_o(&p_lds[w][llo][32 * ks + 8 * lhi]);
            short8 vf[8];
#pragma unroll
            for (int ni = 0; ni < 8; ++ni)
                vf[ni] = ds_read_b128_o(&Vb[cur][16 * ni + llo][((4 * ks + lhi) ^ (llo & 7)) << 3]);
            asm volatile("s_waitcnt lgkmcnt(0)" ::: "memory");
            __builtin_amdgcn_sched_barrier(0);
            __builtin_amdgcn_s_setprio(1);
#pragma unroll
            for (int ni = 0; ni < 8; ++ni)
                o_acc[ni] = __builtin_amdgcn_mfma_f32_16x16x32_bf16(pa, vf[ni], o_acc[ni], 0, 0, 0);
            __builtin_amdgcn_s_setprio(0);
        }

        __syncthreads();   // drains prefetch vmcnt + frees buf[cur]
        cur ^= 1;
    }

    float lsum = l_p;
    lsum += __shfl_xor(lsum, 16);
    lsum += __shfl_xor(lsum, 32);
#pragma unroll
    for (int r = 0; r < 4; ++r) {
        float lr  = __shfl(lsum, 4 * lhi + r);
        float inv = 1.f / lr;
        int qrow2 = q0 + 16 * w + 4 * lhi + r;
#pragma unroll
        for (int ni = 0; ni < 8; ++ni)
            aout[(size_t)qrow2 * DM + h * HD + 16 * ni + llo] = f2bf(o_acc[ni][r] * inv);
    }
}

// ---------------- combine 4 bf16 split-K partials + bias ----------------------
__global__ __launch_bounds__(256)
void combine4_kernel(const u16* __restrict__ p, const float* __restrict__ bias,
                     float* __restrict__ out)
{
    size_t i = ((size_t)blockIdx.x * 256 + threadIdx.x) * 8;
    short8 a0 = *(const short8*)(p + i);
    short8 a1 = *(const short8*)(p + (size_t)CTX * DM + i);
    short8 a2 = *(const short8*)(p + 2 * (size_t)CTX * DM + i);
    short8 a3 = *(const short8*)(p + 3 * (size_t)CTX * DM + i);
    int dbase = (int)(i & (DM - 1));
    float4 bv0 = *(const float4*)(bias + dbase);
    float4 bv1 = *(const float4*)(bias + dbase + 4);
    float r[8];
    float bvv[8] = {bv0.x, bv0.y, bv0.z, bv0.w, bv1.x, bv1.y, bv1.z, bv1.w};
#pragma unroll
    for (int j = 0; j < 8; ++j)
        r[j] = (bf2f((u16)a0[j]) + bf2f((u16)a1[j]))
             + (bf2f((u16)a2[j]) + bf2f((u16)a3[j])) + bvv[j];
    *(float4*)(out + i)     = (float4){r[0], r[1], r[2], r[3]};
    *(float4*)(out + i + 4) = (float4){r[4], r[5], r[6], r[7]};
}

// ------------------------------- launcher ------------------------------------
extern "C" void kernel_launch(void* const* d_in, const int* in_sizes, int n_in,
                              void* d_out, int out_size, void* d_ws, size_t ws_size,
                              hipStream_t stream)
{
    const float* x   = (const float*)d_in[0];
    const float* qng = (const float*)d_in[1];
    const float* qnb = (const float*)d_in[2];
    const float* kng = (const float*)d_in[3];
    const float* knb = (const float*)d_in[4];
    const float* Wq  = (const float*)d_in[5];
    const float* bq  = (const float*)d_in[6];
    const float* Wkv = (const float*)d_in[7];
    const float* bkv = (const float*)d_in[8];
    const float* Wo  = (const float*)d_in[9];
    const float* bo  = (const float*)d_in[10];
    const float* lng = (const float*)d_in[11];
    const float* lnb = (const float*)d_in[12];
    float* out = (float*)d_out;

    uint8_t* ws = (uint8_t*)d_ws;
    size_t off = 0;
    auto alloc = [&](size_t bytes) -> void* {
        void* p = ws + off;
        off += (bytes + 255) & ~(size_t)255;
        return p;
    };
    u16*   WqT  = (u16*)alloc((size_t)DM * DM * 2);
    u16*   WkvT = (u16*)alloc((size_t)2 * DM * DM * 2);
    u16*   WoT  = (u16*)alloc((size_t)DM * DM * 2);
    u16*   Aq   = (u16*)alloc((size_t)CTX * DM * 2);
    u16*   Akv  = (u16*)alloc((size_t)CTX * DM * 2);
    float* ftab = (float*)alloc((size_t)CTX * 64 * 2 * 4);
    u16*   Qf   = (u16*)alloc((size_t)CTX * DM * 2);
    u16*   Kf   = (u16*)alloc((size_t)CTX * DM * 2);
    u16*   vTB  = (u16*)alloc((size_t)CTX * DM * 2);
    u16*   qnB  = (u16*)alloc((size_t)CTX * DM * 2);
    u16*   knB  = (u16*)alloc((size_t)CTX * DM * 2);
    u16*   aB   = (u16*)alloc((size_t)CTX * DM * 2);
    u16*   oprt = (u16*)alloc((size_t)4 * CTX * DM * 2);
    (void)ws_size; (void)in_sizes; (void)n_in; (void)out_size;

    transpose_all_kernel<<<dim3(DM / 32, DM / 32, 4), dim3(32, 8), 0, stream>>>(
        Wq, Wo, Wkv, WqT, WoT, WkvT);

    ln_stats_kernel<<<CTX, 256, 0, stream>>>(x, qng, qnb, kng, knb, Aq, Akv, ftab);

    qkv_gemm256_kernel<<<dim3(384), 256, 0, stream>>>(
        Aq, Akv, WqT, WkvT, bq, bkv, Qf, Kf, vTB);

    const float qk_scale = 0.29730177875068026f;                       // 128^-0.25
    const float fold_q   = 0.08838834764831845f * 1.4426950408889634f; // 1/sqrt(128)*log2(e)
    rot_ln_kernel<<<CTX, 256, 0, stream>>>(
        Qf, Kf, ftab, lng, lnb, qnB, knB, qk_scale, fold_q);

    attn_kernel<<<dim3(CTX / 64, NH), 256, 0, stream>>>(qnB, knB, vTB, aB);

    oproj_gemm256_kernel<<<dim3(256), 512, 0, stream>>>(aB, WoT, oprt);
    combine4_kernel<<<(CTX * DM) / 2048, 256, 0, stream>>>(oprt, bo, out);
}

// Round 10
// 175.377 us; speedup vs baseline: 1.6398x; 1.0067x over previous
//
#include <hip/hip_runtime.h>
#include <stdint.h>
#include <math.h>

#define CTX 2048
#define DM  2048
#define NH  16
#define HD  128

typedef __attribute__((ext_vector_type(8))) short short8;   // 8 x bf16 (4 VGPRs)
typedef __attribute__((ext_vector_type(4))) float f32x4;    // MFMA acc
typedef unsigned short u16;

__device__ __forceinline__ u16 f2bf(float f) {
    unsigned u = __float_as_uint(f);
    unsigned r = u + 0x7fffu + ((u >> 16) & 1u);   // RTNE
    return (u16)(r >> 16);
}
__device__ __forceinline__ float bf2f(u16 h) {
    return __uint_as_float(((unsigned)h) << 16);
}

// Opaque LDS read: invisible to SIInsertWaitcnts' LDS-DMA alias tracking, so
// the compiler cannot insert vmcnt(0) drains before it. Ordering enforced
// manually: counted lgkmcnt + sched_barrier(0) before every consumer (rule #18).
__device__ __forceinline__ short8 ds_read_b128_o(const void* p) {
    short8 r;
    asm volatile("ds_read_b128 %0, %1"
                 : "=v"(r)
                 : "v"((const __attribute__((address_space(3))) void*)p));
    return r;
}

// ------- merged weight transpose + f32->bf16 (W[K][N] -> WT[N][K]), 4 slabs ---
__global__ __launch_bounds__(256)
void transpose_all_kernel(const float* __restrict__ Wq, const float* __restrict__ Wo,
                          const float* __restrict__ Wkv,
                          u16* __restrict__ WqT, u16* __restrict__ WoT, u16* __restrict__ WkvT)
{
    __shared__ float tile[32][33];
    int z = blockIdx.z;
    const float* S; u16* D; int nsrc, c0, r0;
    if (z == 0)      { S = Wq;  D = WqT;  nsrc = DM;     c0 = 0;  r0 = 0;    }
    else if (z == 1) { S = Wo;  D = WoT;  nsrc = DM;     c0 = 0;  r0 = 0;    }
    else if (z == 2) { S = Wkv; D = WkvT; nsrc = 2 * DM; c0 = 0;  r0 = 0;    }
    else             { S = Wkv; D = WkvT; nsrc = 2 * DM; c0 = DM; r0 = DM;   }
    int k0 = blockIdx.x * 32, n0 = blockIdx.y * 32;
    int tx = threadIdx.x, ty = threadIdx.y;          // 32 x 8
#pragma unroll
    for (int j = 0; j < 4; ++j) {
        int kk = ty + 8 * j;
        tile[kk][tx] = S[(size_t)(k0 + kk) * nsrc + c0 + n0 + tx];
    }
    __syncthreads();
#pragma unroll
    for (int j = 0; j < 4; ++j) {
        int nn = ty + 8 * j;
        D[(size_t)(r0 + n0 + nn) * DM + k0 + tx] = f2bf(tile[tx][nn]);
    }
}

// -------- LN stats + normalized A matrices (bf16) + rotary factor table -------
__global__ __launch_bounds__(256)
void ln_stats_kernel(const float* __restrict__ x,
                     const float* __restrict__ qg, const float* __restrict__ qb,
                     const float* __restrict__ kg, const float* __restrict__ kb,
                     u16* __restrict__ Aq, u16* __restrict__ Akv, float* __restrict__ ftab)
{
    int c = blockIdx.x, t = threadIdx.x;
    const float* row = x + (size_t)c * DM;
    float4 v0 = *(const float4*)(row + t * 8);
    float4 v1 = *(const float4*)(row + t * 8 + 4);
    float vals[8] = {v0.x, v0.y, v0.z, v0.w, v1.x, v1.y, v1.z, v1.w};
    float s = 0.f, ss = 0.f;
#pragma unroll
    for (int j = 0; j < 8; ++j) { s += vals[j]; ss += vals[j] * vals[j]; }
#pragma unroll
    for (int off = 32; off; off >>= 1) { s += __shfl_xor(s, off); ss += __shfl_xor(ss, off); }
    __shared__ float red[8];
    int w = t >> 6;
    if ((t & 63) == 0) { red[w] = s; red[4 + w] = ss; }
    __syncthreads();
    float st  = red[0] + red[1] + red[2] + red[3];
    float sst = red[4] + red[5] + red[6] + red[7];
    float mu   = st * (1.f / DM);
    float var  = sst * (1.f / DM) - mu * mu;
    float rstd = rsqrtf(var + 1e-5f);
    if (t < 64) {                         // rotary table, m folded in
        const float LT64 = 10.30895266f / 64.f;   // ln(30000)/64
        float m = sqrtf(sst);
        float sn, cs;
        sincosf((float)c * ((float)t * LT64), &sn, &cs);
        float2 wv = {m * cs, m * sn};
        *(float2*)(ftab + ((size_t)c * 64 + t) * 2) = wv;
    }
    short8 aq, akv;
#pragma unroll
    for (int j = 0; j < 8; ++j) {
        int d = t * 8 + j;
        float xh = (vals[j] - mu) * rstd;
        aq[j]  = (short)f2bf(xh * qg[d] + qb[d]);
        akv[j] = (short)f2bf(xh * kg[d] + kb[d]);
    }
    *(short8*)(Aq  + (size_t)c * DM + t * 8) = aq;
    *(short8*)(Akv + (size_t)c * DM + t * 8) = akv;
}

// ---------------- fused QKV projection GEMM -----------------------------------
// v5: 128x256 tile, BK=64, 4 waves (1Mx4N), SINGLE-buffered 48 KiB LDS ->
// 2 blocks/CU co-resident, grid 384 = all 256 CUs busy. Cross-block TLP covers
// the stage stall and lgkm drains. Proven 61us / passing.
__global__ __launch_bounds__(256, 2)
void qkv_gemm256_kernel(const u16* __restrict__ Aq, const u16* __restrict__ Akv,
                        const u16* __restrict__ WqT, const u16* __restrict__ WkvT,
                        const float* __restrict__ bq, const float* __restrict__ bkv,
                        u16* __restrict__ Qf, u16* __restrict__ Kf, u16* __restrict__ vT)
{
    __shared__ __align__(16) u16 As[128][64];         // 16 KiB
    __shared__ __align__(16) u16 Bs[2][128][64];      // 32 KiB

    constexpr int NT = DM / 64;                       // 32 K-tiles

    // XCD swizzle: 384 blocks, 48 contiguous per XCD (384 % 8 == 0, bijective).
    int lin = blockIdx.x;
    int swz = (lin & 7) * 48 + (lin >> 3);
    int mt  = swz & 15;         // M tile 0..15 (128 rows)
    int ng  = swz >> 4;         // 0..23
    int seg = ng >> 3;          // 0:Q 1:K 2:V
    int nt  = ng & 7;           // N tile 0..7 (256 cols)

    const u16* Amat; const u16* Bmat; const float* bias; u16* outp; bool rowbias;
    if (seg == 0) {
        Amat = Aq  + (size_t)mt * 128 * DM;
        Bmat = WqT + (size_t)nt * 256 * DM;
        bias = bq + nt * 256;
        outp = Qf + (size_t)mt * 128 * DM + nt * 256;
        rowbias = false;
    } else if (seg == 1) {
        Amat = Akv  + (size_t)mt * 128 * DM;
        Bmat = WkvT + (size_t)nt * 256 * DM;
        bias = bkv + nt * 256;
        outp = Kf + (size_t)mt * 128 * DM + nt * 256;
        rowbias = false;
    } else {
        Amat = WkvT + (size_t)(DM + mt * 128) * DM;   // V dims as GEMM rows
        Bmat = Akv  + (size_t)nt * 256 * DM;          // context as GEMM cols
        bias = bkv + DM + mt * 128;                   // per-row bias
        outp = vT + (size_t)mt * 128 * CTX + nt * 256;
        rowbias = true;
    }

    int tid = threadIdx.x;
    int wid = tid >> 6, l = tid & 63;                 // 4 waves, wave = N slice
    int wc = wid;                                     // 0..3
    int lhi = l >> 4, llo = l & 15;
    int srow  = l >> 3;                               // staging row within 8-row group
    int sunit = (l & 7) ^ srow;                       // inverse-swizzled 16B unit

    // stage tile kt: A 128x64 (4 loads/wave), B 2x128x64 (8 loads/wave)
    auto stage = [&](int kt) {
#pragma unroll
        for (int rd = 0; rd < 4; ++rd) {
            int r = wid * 32 + rd * 8;
            const u16* src = Amat + (size_t)(r + srow) * DM + kt * 64 + sunit * 8;
            __builtin_amdgcn_global_load_lds((const __attribute__((address_space(1))) void*)src,
                (__attribute__((address_space(3))) void*)&As[r][0], 16, 0, 0);
        }
#pragma unroll
        for (int h = 0; h < 2; ++h)
#pragma unroll
            for (int rd = 0; rd < 4; ++rd) {
                int r = wid * 32 + rd * 8;
                const u16* src = Bmat + (size_t)(h * 128 + r + srow) * DM + kt * 64 + sunit * 8;
                __builtin_amdgcn_global_load_lds((const __attribute__((address_space(1))) void*)src,
                    (__attribute__((address_space(3))) void*)&Bs[h][r][0], 16, 0, 0);
            }
    };

    f32x4 acc[8][4] = {};                 // accumulator
    short8 a[4][2];                       // reused for a03 then a47 (VGPR cap)
    short8 b0[2][2], b1[2][2];
    int bhalf = wc >> 1, brow = (wc & 1) * 64;

    stage(0);
    asm volatile("s_waitcnt vmcnt(0)" ::: "memory");
    __builtin_amdgcn_s_barrier();

    for (int kt = 0; kt < NT; ++kt) {
        // ---- reads: b0 (4) + a03 (8) + b1 (4) -------------------------------
#pragma unroll
        for (int ni = 0; ni < 2; ++ni)
#pragma unroll
            for (int ks = 0; ks < 2; ++ks) {
                int r = brow + 16 * ni + llo;
                b0[ni][ks] = ds_read_b128_o(&Bs[bhalf][r][((ks * 4 + lhi) ^ (llo & 7)) << 3]);
            }
#pragma unroll
        for (int mi = 0; mi < 4; ++mi)
#pragma unroll
            for (int ks = 0; ks < 2; ++ks) {
                int r = 16 * mi + llo;
                a[mi][ks] = ds_read_b128_o(&As[r][((ks * 4 + lhi) ^ (llo & 7)) << 3]);
            }
#pragma unroll
        for (int ni = 0; ni < 2; ++ni)
#pragma unroll
            for (int ks = 0; ks < 2; ++ks) {
                int r = brow + 16 * (2 + ni) + llo;
                b1[ni][ks] = ds_read_b128_o(&Bs[bhalf][r][((ks * 4 + lhi) ^ (llo & 7)) << 3]);
            }

        // ---- q00 ------------------------------------------------------------
        asm volatile("s_waitcnt lgkmcnt(4)" ::: "memory");
        __builtin_amdgcn_sched_barrier(0);
        __builtin_amdgcn_s_setprio(1);
#pragma unroll
        for (int ks = 0; ks < 2; ++ks)
#pragma unroll
            for (int mi = 0; mi < 4; ++mi)
#pragma unroll
                for (int ni = 0; ni < 2; ++ni)
                    acc[mi][ni] = __builtin_amdgcn_mfma_f32_16x16x32_bf16(
                        a[mi][ks], b0[ni][ks], acc[mi][ni], 0, 0, 0);
        __builtin_amdgcn_s_setprio(0);

        // ---- q01 ------------------------------------------------------------
        asm volatile("s_waitcnt lgkmcnt(0)" ::: "memory");
        __builtin_amdgcn_sched_barrier(0);
        __builtin_amdgcn_s_setprio(1);
#pragma unroll
        for (int ks = 0; ks < 2; ++ks)
#pragma unroll
            for (int mi = 0; mi < 4; ++mi)
#pragma unroll
                for (int ni = 0; ni < 2; ++ni)
                    acc[mi][2 + ni] = __builtin_amdgcn_mfma_f32_16x16x32_bf16(
                        a[mi][ks], b1[ni][ks], acc[mi][2 + ni], 0, 0, 0);
        __builtin_amdgcn_s_setprio(0);

        // ---- read a47 (reuse regs); q11, q10 --------------------------------
#pragma unroll
        for (int mi = 0; mi < 4; ++mi)
#pragma unroll
            for (int ks = 0; ks < 2; ++ks) {
                int r = 16 * (4 + mi) + llo;
                a[mi][ks] = ds_read_b128_o(&As[r][((ks * 4 + lhi) ^ (llo & 7)) << 3]);
            }
        asm volatile("s_waitcnt lgkmcnt(0)" ::: "memory");
        __builtin_amdgcn_sched_barrier(0);
        __builtin_amdgcn_s_setprio(1);
#pragma unroll
        for (int ks = 0; ks < 2; ++ks)
#pragma unroll
            for (int mi = 0; mi < 4; ++mi)
#pragma unroll
                for (int ni = 0; ni < 2; ++ni)
                    acc[4 + mi][2 + ni] = __builtin_amdgcn_mfma_f32_16x16x32_bf16(
                        a[mi][ks], b1[ni][ks], acc[4 + mi][2 + ni], 0, 0, 0);
#pragma unroll
        for (int ks = 0; ks < 2; ++ks)
#pragma unroll
            for (int mi = 0; mi < 4; ++mi)
#pragma unroll
                for (int ni = 0; ni < 2; ++ni)
                    acc[4 + mi][ni] = __builtin_amdgcn_mfma_f32_16x16x32_bf16(
                        a[mi][ks], b0[ni][ks], acc[4 + mi][ni], 0, 0, 0);
        __builtin_amdgcn_s_setprio(0);

        // ---- all reads of S retired block-wide -> restage -------------------
        __builtin_amdgcn_s_barrier();
        if (kt + 1 < NT) {
            stage(kt + 1);
            asm volatile("s_waitcnt vmcnt(0)" ::: "memory");
            __builtin_amdgcn_s_barrier();
        }
    }

    // ---------------- epilogue: bias + bf16 store ----------------------------
    int cbase = 64 * wc;
    if (!rowbias) {
#pragma unroll
        for (int ni = 0; ni < 4; ++ni) {
            float bv = bias[cbase + 16 * ni + llo];
#pragma unroll
            for (int mi = 0; mi < 8; ++mi)
#pragma unroll
                for (int rr = 0; rr < 4; ++rr) {
                    int gr = 16 * mi + 4 * lhi + rr;
                    outp[(size_t)gr * DM + cbase + 16 * ni + llo] = f2bf(acc[mi][ni][rr] + bv);
                }
        }
    } else {
#pragma unroll
        for (int mi = 0; mi < 8; ++mi)
#pragma unroll
            for (int rr = 0; rr < 4; ++rr) {
                int gr = 16 * mi + 4 * lhi + rr;
                float bv = bias[gr];
#pragma unroll
                for (int ni = 0; ni < 4; ++ni)
                    outp[(size_t)gr * CTX + cbase + 16 * ni + llo] = f2bf(acc[mi][ni][rr] + bv);
            }
    }
}

// ---------------- O-projection GEMM: 256^2 tile, 4-way split-K ----------------
__global__ __launch_bounds__(512, 2)
void oproj_gemm256_kernel(const u16* __restrict__ A, const u16* __restrict__ BT,
                          u16* __restrict__ outp)
{
    __shared__ __align__(16) u16 As[2][2][128][64];
    __shared__ __align__(16) u16 Bs[2][2][128][64];

    constexpr int NT = 8;                             // 8 K-tiles = 512 deep

    // XCD swizzle: 256 blocks, 32 contiguous per XCD (256 % 8 == 0, bijective)
    int lin = blockIdx.x;
    int swz = (lin & 7) * 32 + (lin >> 3);
    int kz  = swz >> 6;          // K split 0..3
    int rem = swz & 63;
    int mt  = rem & 7;
    int nt  = rem >> 3;

    const u16* Amat = A  + (size_t)mt * 256 * DM + kz * 512;
    const u16* Bmat = BT + (size_t)nt * 256 * DM + kz * 512;
    u16* out = outp + (size_t)kz * CTX * DM + (size_t)mt * 256 * DM + nt * 256;

    int tid = threadIdx.x;
    int wid = tid >> 6, l = tid & 63;
    int wr = wid >> 2, wc = wid & 3;
    int lhi = l >> 4, llo = l & 15;
    int srow  = l >> 3;
    int sunit = (l & 7) ^ srow;

    auto stageA = [&](int kt, int h) {
#pragma unroll
        for (int rd = 0; rd < 2; ++rd) {
            const u16* src = Amat + (size_t)(h * 128 + rd * 64 + wid * 8 + srow) * DM
                             + kt * 64 + sunit * 8;
            __builtin_amdgcn_global_load_lds((const __attribute__((address_space(1))) void*)src,
                (__attribute__((address_space(3))) void*)&As[kt & 1][h][rd * 64 + wid * 8][0],
                16, 0, 0);
        }
    };
    auto stageB = [&](int kt, int h) {
#pragma unroll
        for (int rd = 0; rd < 2; ++rd) {
            const u16* src = Bmat + (size_t)(h * 128 + rd * 64 + wid * 8 + srow) * DM
                             + kt * 64 + sunit * 8;
            __builtin_amdgcn_global_load_lds((const __attribute__((address_space(1))) void*)src,
                (__attribute__((address_space(3))) void*)&Bs[kt & 1][h][rd * 64 + wid * 8][0],
                16, 0, 0);
        }
    };

    f32x4 acc[8][4] = {};
    short8 a[4][2];
    short8 b0[2][2], b1[2][2];
    int bhalf = wc >> 1, brow = (wc & 1) * 64;

    stageA(0, 0); stageA(0, 1); stageB(0, 0); stageB(0, 1);
    stageA(1, 0); stageA(1, 1); stageB(1, 0); stageB(1, 1);
    asm volatile("s_waitcnt vmcnt(8)" ::: "memory");
    __builtin_amdgcn_s_barrier();

    for (int kt = 0; kt < NT; ++kt) {
        int buf = kt & 1;

#pragma unroll
        for (int ni = 0; ni < 2; ++ni)
#pragma unroll
            for (int ks = 0; ks < 2; ++ks) {
                int r = brow + 16 * ni + llo;
                b0[ni][ks] = ds_read_b128_o(&Bs[buf][bhalf][r][((ks * 4 + lhi) ^ (llo & 7)) << 3]);
            }
#pragma unroll
        for (int mi = 0; mi < 4; ++mi)
#pragma unroll
            for (int ks = 0; ks < 2; ++ks) {
                int r = 16 * mi + llo;
                a[mi][ks] = ds_read_b128_o(&As[buf][wr][r][((ks * 4 + lhi) ^ (llo & 7)) << 3]);
            }
#pragma unroll
        for (int ni = 0; ni < 2; ++ni)
#pragma unroll
            for (int ks = 0; ks < 2; ++ks) {
                int r = brow + 16 * (2 + ni) + llo;
                b1[ni][ks] = ds_read_b128_o(&Bs[buf][bhalf][r][((ks * 4 + lhi) ^ (llo & 7)) << 3]);
            }

        asm volatile("s_waitcnt lgkmcnt(4)" ::: "memory");
        __builtin_amdgcn_sched_barrier(0);
        __builtin_amdgcn_s_setprio(1);
#pragma unroll
        for (int ks = 0; ks < 2; ++ks)
#pragma unroll
            for (int mi = 0; mi < 4; ++mi)
#pragma unroll
                for (int ni = 0; ni < 2; ++ni)
                    acc[mi][ni] = __builtin_amdgcn_mfma_f32_16x16x32_bf16(
                        a[mi][ks], b0[ni][ks], acc[mi][ni], 0, 0, 0);
        __builtin_amdgcn_s_setprio(0);

        asm volatile("s_waitcnt lgkmcnt(0)" ::: "memory");
        __builtin_amdgcn_sched_barrier(0);
        __builtin_amdgcn_s_setprio(1);
#pragma unroll
        for (int ks = 0; ks < 2; ++ks)
#pragma unroll
            for (int mi = 0; mi < 4; ++mi)
#pragma unroll
                for (int ni = 0; ni < 2; ++ni)
                    acc[mi][2 + ni] = __builtin_amdgcn_mfma_f32_16x16x32_bf16(
                        a[mi][ks], b1[ni][ks], acc[mi][2 + ni], 0, 0, 0);
        __builtin_amdgcn_s_setprio(0);

        __builtin_amdgcn_s_barrier();   // #1

        if (kt + 2 < NT) { stageB(kt + 2, 0); stageB(kt + 2, 1); }
#pragma unroll
        for (int mi = 0; mi < 4; ++mi)
#pragma unroll
            for (int ks = 0; ks < 2; ++ks) {
                int r = 16 * (4 + mi) + llo;
                a[mi][ks] = ds_read_b128_o(&As[buf][wr][r][((ks * 4 + lhi) ^ (llo & 7)) << 3]);
            }

        asm volatile("s_waitcnt lgkmcnt(0)" ::: "memory");
        __builtin_amdgcn_sched_barrier(0);
        __builtin_amdgcn_s_setprio(1);
#pragma unroll
        for (int ks = 0; ks < 2; ++ks)
#pragma unroll
            for (int mi = 0; mi < 4; ++mi)
#pragma unroll
                for (int ni = 0; ni < 2; ++ni)
                    acc[4 + mi][2 + ni] = __builtin_amdgcn_mfma_f32_16x16x32_bf16(
                        a[mi][ks], b1[ni][ks], acc[4 + mi][2 + ni], 0, 0, 0);
        __builtin_amdgcn_s_setprio(0);

        __builtin_amdgcn_s_barrier();   // #2

        if (kt + 2 < NT) { stageA(kt + 2, 0); stageA(kt + 2, 1); }
        __builtin_amdgcn_s_setprio(1);
#pragma unroll
        for (int ks = 0; ks < 2; ++ks)
#pragma unroll
            for (int mi = 0; mi < 4; ++mi)
#pragma unroll
                for (int ni = 0; ni < 2; ++ni)
                    acc[4 + mi][ni] = __builtin_amdgcn_mfma_f32_16x16x32_bf16(
                        a[mi][ks], b0[ni][ks], acc[4 + mi][ni], 0, 0, 0);
        __builtin_amdgcn_s_setprio(0);

        if (kt + 2 < NT)      { asm volatile("s_waitcnt vmcnt(8)" ::: "memory"); }
        else if (kt + 1 < NT) { asm volatile("s_waitcnt vmcnt(0)" ::: "memory"); }
        __builtin_amdgcn_s_barrier();   // #3
    }

    int rbase = 128 * wr;
    int cbase = 64 * wc;
#pragma unroll
    for (int ni = 0; ni < 4; ++ni) {
#pragma unroll
        for (int mi = 0; mi < 8; ++mi)
#pragma unroll
            for (int rr = 0; rr < 4; ++rr) {
                int gr = rbase + 16 * mi + 4 * lhi + rr;
                out[(size_t)gr * DM + cbase + 16 * ni + llo] = f2bf(acc[mi][ni][rr]);
            }
    }
}

// -------- table-driven rotary + per-head LN (one block per token row) ---------
__global__ __launch_bounds__(256)
void rot_ln_kernel(const u16* __restrict__ Qf, const u16* __restrict__ Kf,
                   const float* __restrict__ ftab,
                   const float* __restrict__ g, const float* __restrict__ b,
                   u16* __restrict__ qnB, u16* __restrict__ knB,
                   float qk_scale, float fold_q)
{
    int c = blockIdx.x, t = threadIdx.x;
    int h  = t >> 4;
    int dl = (t & 15) * 8;
    const float* tab = ftab + ((size_t)c * 64 + (dl >> 1)) * 2;
    float fre[4], fim[4];
#pragma unroll
    for (int p = 0; p < 4; ++p) { fre[p] = tab[2 * p]; fim[p] = tab[2 * p + 1]; }
    float gv[8], bv2[8];
#pragma unroll
    for (int j = 0; j < 8; ++j) { gv[j] = g[dl + j]; bv2[j] = b[dl + j]; }

#pragma unroll
    for (int z = 0; z < 2; ++z) {
        const u16* src = z ? Kf : Qf;
        u16* dst = z ? knB : qnB;
        float fold = z ? 1.f : fold_q;
        short8 vv = *(const short8*)(src + (size_t)c * DM + t * 8);
        float o[8];
        float s = 0.f, ss = 0.f;
#pragma unroll
        for (int p = 0; p < 4; ++p) {
            float a  = bf2f((u16)vv[2 * p])     * qk_scale;
            float b2 = bf2f((u16)vv[2 * p + 1]) * qk_scale;
            float o0 = a * fre[p] - b2 * fim[p];
            float o1 = a * fim[p] + b2 * fre[p];
            o[2 * p] = o0; o[2 * p + 1] = o1;
            s += o0 + o1;
            ss += o0 * o0 + o1 * o1;
        }
#pragma unroll
        for (int off = 1; off < 16; off <<= 1) {
            s += __shfl_xor(s, off);
            ss += __shfl_xor(ss, off);
        }
        float mu   = s * (1.f / HD);
        float var  = ss * (1.f / HD) - mu * mu;
        float rstd = rsqrtf(var + 1e-5f);
        short8 r;
#pragma unroll
        for (int j = 0; j < 8; ++j)
            r[j] = (short)f2bf(((o[j] - mu) * rstd * gv[j] + bv2[j]) * fold);
        *(short8*)(dst + ((size_t)h * CTX + c) * HD + dl) = r;
    }
}

// ---------------- causal flash attention v6 ------------------------------------
// v5 + V-prefetch: the 16 V-fragment reads depend only on the staged tile (not
// on P), so they are issued BEFORE the softmax VALU block and retire under it.
// PV's waits become counted: DS ops retire in order (16 vf -> 8 pack-writes ->
// pa0 -> pa1), so lgkm(1) proves everything cluster-0 needs is ready, and
// lgkm(0) covers cluster-1. sched_barrier(0) pins pack-writes before the
// opaque pa reads (same fence as v5).
__global__ __launch_bounds__(256, 2)
void attn_kernel(const u16* __restrict__ qn, const u16* __restrict__ kn,
                 const u16* __restrict__ vT, u16* __restrict__ aout)
{
    __shared__ __align__(16) u16 Kb[2][64][128];
    __shared__ __align__(16) u16 Vb[2][128][64];
    __shared__ __align__(16) u16 p_lds[4][16][72];

    int h  = blockIdx.y;
    int xs = blockIdx.x;
    int qb = (h >= 8) ? (31 - xs) : xs;   // CU load-balance pairing
    int q0 = qb * 64;
    int tid = threadIdx.x, w = tid >> 6, l = tid & 63;
    int lhi = l >> 4, llo = l & 15;

    const u16* qrow = qn + ((size_t)h * CTX + q0 + 16 * w + llo) * HD + 8 * lhi;
    short8 qf[4];
#pragma unroll
    for (int ks = 0; ks < 4; ++ks) qf[ks] = *(const short8*)(qrow + 32 * ks);

    auto stage = [&](int buf, int kv0) {
        int rb = 16 * w;
#pragma unroll
        for (int j = 0; j < 4; ++j) {
            int r = rb + 4 * j + (l >> 4);
            int csw = (l & 15) ^ (r & 15);
            const u16* src = kn + ((size_t)h * CTX + kv0 + r) * HD + (csw << 3);
            __builtin_amdgcn_global_load_lds((const __attribute__((address_space(1))) void*)src,
                (__attribute__((address_space(3))) void*)&Kb[buf][rb + 4 * j][0], 16, 0, 0);
        }
        int db = 32 * w;
#pragma unroll
        for (int j = 0; j < 4; ++j) {
            int d = db + 8 * j + (l >> 3);
            int csw = (l & 7) ^ (d & 7);
            const u16* src = vT + ((size_t)h * HD + d) * CTX + kv0 + (csw << 3);
            __builtin_amdgcn_global_load_lds((const __attribute__((address_space(1))) void*)src,
                (__attribute__((address_space(3))) void*)&Vb[buf][db + 8 * j][0], 16, 0, 0);
        }
    };

    float m_s = -1e30f, l_p = 0.f;
    f32x4 o_acc[8];
#pragma unroll
    for (int ni = 0; ni < 8; ++ni) o_acc[ni] = (f32x4){0.f, 0.f, 0.f, 0.f};

    stage(0, 0);
    __syncthreads();

    int cur = 0;
    for (int jt = 0; jt <= qb; ++jt) {
        if (jt < qb) stage(cur ^ 1, (jt + 1) * 64);   // prefetch overlaps compute

        // ---- QK^T: opaque reads, 2 pipelined K banks ------------------------
        f32x4 sacc[4] = {};
        short8 kf0[4], kf1[4];
#pragma unroll
        for (int ni = 0; ni < 4; ++ni)
            kf0[ni] = ds_read_b128_o(&Kb[cur][16 * ni + llo][(lhi ^ llo) << 3]);
#pragma unroll
        for (int ni = 0; ni < 4; ++ni)
            kf1[ni] = ds_read_b128_o(&Kb[cur][16 * ni + llo][((4 + lhi) ^ llo) << 3]);

        asm volatile("s_waitcnt lgkmcnt(4)" ::: "memory");   // kf0 ready
        __builtin_amdgcn_sched_barrier(0);
        __builtin_amdgcn_s_setprio(1);
#pragma unroll
        for (int ni = 0; ni < 4; ++ni)
            sacc[ni] = __builtin_amdgcn_mfma_f32_16x16x32_bf16(kf0[ni], qf[0], sacc[ni], 0, 0, 0);
        __builtin_amdgcn_s_setprio(0);

#pragma unroll
        for (int ni = 0; ni < 4; ++ni)
            kf0[ni] = ds_read_b128_o(&Kb[cur][16 * ni + llo][((8 + lhi) ^ llo) << 3]);
        asm volatile("s_waitcnt lgkmcnt(4)" ::: "memory");   // kf1 ready
        __builtin_amdgcn_sched_barrier(0);
        __builtin_amdgcn_s_setprio(1);
#pragma unroll
        for (int ni = 0; ni < 4; ++ni)
            sacc[ni] = __builtin_amdgcn_mfma_f32_16x16x32_bf16(kf1[ni], qf[1], sacc[ni], 0, 0, 0);
        __builtin_amdgcn_s_setprio(0);

#pragma unroll
        for (int ni = 0; ni < 4; ++ni)
            kf1[ni] = ds_read_b128_o(&Kb[cur][16 * ni + llo][((12 + lhi) ^ llo) << 3]);
        asm volatile("s_waitcnt lgkmcnt(4)" ::: "memory");   // kf0 (ks=2) ready
        __builtin_amdgcn_sched_barrier(0);
        __builtin_amdgcn_s_setprio(1);
#pragma unroll
        for (int ni = 0; ni < 4; ++ni)
            sacc[ni] = __builtin_amdgcn_mfma_f32_16x16x32_bf16(kf0[ni], qf[2], sacc[ni], 0, 0, 0);
        __builtin_amdgcn_s_setprio(0);

        asm volatile("s_waitcnt lgkmcnt(0)" ::: "memory");   // kf1 (ks=3) ready
        __builtin_amdgcn_sched_barrier(0);
        __builtin_amdgcn_s_setprio(1);
#pragma unroll
        for (int ni = 0; ni < 4; ++ni)
            sacc[ni] = __builtin_amdgcn_mfma_f32_16x16x32_bf16(kf1[ni], qf[3], sacc[ni], 0, 0, 0);
        __builtin_amdgcn_s_setprio(0);

        // ---- V prefetch: issue all 16 V reads; they retire under softmax ----
        short8 vfA[8], vfB[8];
#pragma unroll
        for (int ni = 0; ni < 8; ++ni)
            vfA[ni] = ds_read_b128_o(&Vb[cur][16 * ni + llo][(lhi ^ (llo & 7)) << 3]);
#pragma unroll
        for (int ni = 0; ni < 8; ++ni)
            vfB[ni] = ds_read_b128_o(&Vb[cur][16 * ni + llo][((4 + lhi) ^ (llo & 7)) << 3]);

        if (jt == qb) {                  // causal mask inside diagonal tile
            int qloc = 16 * w + llo;
#pragma unroll
            for (int ni = 0; ni < 4; ++ni)
#pragma unroll
                for (int r = 0; r < 4; ++r)
                    if (16 * ni + 4 * lhi + r > qloc) sacc[ni][r] = -INFINITY;
        }

        // speculative P with OLD running max (no cross-lane wait)
        float pv[16];
#pragma unroll
        for (int ni = 0; ni < 4; ++ni)
#pragma unroll
            for (int r = 0; r < 4; ++r) pv[4 * ni + r] = exp2f(sacc[ni][r] - m_s);

        // per-lane local max only; __any supplies the cross-lane OR
        float mx = sacc[0][0];
#pragma unroll
        for (int ni = 0; ni < 4; ++ni)
#pragma unroll
            for (int r = 0; r < 4; ++r) mx = fmaxf(mx, sacc[ni][r]);

        if (__any(mx > m_s + 8.f)) {     // rare path: full reduce + rescale
            mx = fmaxf(mx, __shfl_xor(mx, 16));
            mx = fmaxf(mx, __shfl_xor(mx, 32));
            float mnew = fmaxf(m_s, mx);
            float fac = exp2f(m_s - mnew);
#pragma unroll
            for (int r = 0; r < 4; ++r) {
                float fr = __shfl(fac, 4 * lhi + r);
#pragma unroll
                for (int ni = 0; ni < 8; ++ni) o_acc[ni][r] *= fr;
            }
#pragma unroll
            for (int ni = 0; ni < 4; ++ni)
#pragma unroll
                for (int r = 0; r < 4; ++r) pv[4 * ni + r] = exp2f(sacc[ni][r] - mnew);
            l_p *= fac;
            m_s = mnew;
        }

        // pack P -> p_lds (wave-private region; DS pipe is in-order per wave)
#pragma unroll
        for (int ni = 0; ni < 4; ++ni)
#pragma unroll
            for (int hf = 0; hf < 2; ++hf) {
                unsigned pk;
                asm("v_cvt_pk_bf16_f32 %0, %1, %2" : "=v"(pk)
                    : "v"(pv[4 * ni + 2 * hf]), "v"(pv[4 * ni + 2 * hf + 1]));
                *(unsigned*)&p_lds[w][llo][16 * ni + 4 * lhi + 2 * hf] = pk;
            }

        // deferred l: per-lane partial only (cross-lane reduce in epilogue)
        float ps = 0.f;
#pragma unroll
        for (int j = 0; j < 16; ++j) ps += pv[j];
        l_p += ps;

        // pin pack-writes in program order before the opaque pa reads
        __builtin_amdgcn_sched_barrier(0);

        // ---- O += P . V; counted waits (retire order: vf, writes, pa0, pa1) -
        short8 pa0 = ds_read_b128_o(&p_lds[w][llo][8 * lhi]);
        short8 pa1 = ds_read_b128_o(&p_lds[w][llo][32 + 8 * lhi]);

        asm volatile("s_waitcnt lgkmcnt(1)" ::: "memory");   // all but pa1
        __builtin_amdgcn_sched_barrier(0);
        __builtin_amdgcn_s_setprio(1);
#pragma unroll
        for (int ni = 0; ni < 8; ++ni)
            o_acc[ni] = __builtin_amdgcn_mfma_f32_16x16x32_bf16(pa0, vfA[ni], o_acc[ni], 0, 0, 0);
        __builtin_amdgcn_s_setprio(0);

        asm volatile("s_waitcnt lgkmcnt(0)" ::: "memory");   // pa1
        __builtin_amdgcn_sched_barrier(0);
        __builtin_amdgcn_s_setprio(1);
#pragma unroll
        for (int ni = 0; ni < 8; ++ni)
            o_acc[ni] = __builtin_amdgcn_mfma_f32_16x16x32_bf16(pa1, vfB[ni], o_acc[ni], 0, 0, 0);
        __builtin_amdgcn_s_setprio(0);

        __syncthreads();   // drains prefetch vmcnt + frees buf[cur]
        cur ^= 1;
    }

    float lsum = l_p;
    lsum += __shfl_xor(lsum, 16);
    lsum += __shfl_xor(lsum, 32);
#pragma unroll
    for (int r = 0; r < 4; ++r) {
        float lr  = __shfl(lsum, 4 * lhi + r);
        float inv = 1.f / lr;
        int qrow2 = q0 + 16 * w + 4 * lhi + r;
#pragma unroll
        for (int ni = 0; ni < 8; ++ni)
            aout[(size_t)qrow2 * DM + h * HD + 16 * ni + llo] = f2bf(o_acc[ni][r] * inv);
    }
}

// ---------------- combine 4 bf16 split-K partials + bias ----------------------
__global__ __launch_bounds__(256)
void combine4_kernel(const u16* __restrict__ p, const float* __restrict__ bias,
                     float* __restrict__ out)
{
    size_t i = ((size_t)blockIdx.x * 256 + threadIdx.x) * 8;
    short8 a0 = *(const short8*)(p + i);
    short8 a1 = *(const short8*)(p + (size_t)CTX * DM + i);
    short8 a2 = *(const short8*)(p + 2 * (size_t)CTX * DM + i);
    short8 a3 = *(const short8*)(p + 3 * (size_t)CTX * DM + i);
    int dbase = (int)(i & (DM - 1));
    float4 bv0 = *(const float4*)(bias + dbase);
    float4 bv1 = *(const float4*)(bias + dbase + 4);
    float r[8];
    float bvv[8] = {bv0.x, bv0.y, bv0.z, bv0.w, bv1.x, bv1.y, bv1.z, bv1.w};
#pragma unroll
    for (int j = 0; j < 8; ++j)
        r[j] = (bf2f((u16)a0[j]) + bf2f((u16)a1[j]))
             + (bf2f((u16)a2[j]) + bf2f((u16)a3[j])) + bvv[j];
    *(float4*)(out + i)     = (float4){r[0], r[1], r[2], r[3]};
    *(float4*)(out + i + 4) = (float4){r[4], r[5], r[6], r[7]};
}

// ------------------------------- launcher ------------------------------------
extern "C" void kernel_launch(void* const* d_in, const int* in_sizes, int n_in,
                              void* d_out, int out_size, void* d_ws, size_t ws_size,
                              hipStream_t stream)
{
    const float* x   = (const float*)d_in[0];
    const float* qng = (const float*)d_in[1];
    const float* qnb = (const float*)d_in[2];
    const float* kng = (const float*)d_in[3];
    const float* knb = (const float*)d_in[4];
    const float* Wq  = (const float*)d_in[5];
    const float* bq  = (const float*)d_in[6];
    const float* Wkv = (const float*)d_in[7];
    const float* bkv = (const float*)d_in[8];
    const float* Wo  = (const float*)d_in[9];
    const float* bo  = (const float*)d_in[10];
    const float* lng = (const float*)d_in[11];
    const float* lnb = (const float*)d_in[12];
    float* out = (float*)d_out;

    uint8_t* ws = (uint8_t*)d_ws;
    size_t off = 0;
    auto alloc = [&](size_t bytes) -> void* {
        void* p = ws + off;
        off += (bytes + 255) & ~(size_t)255;
        return p;
    };
    u16*   WqT  = (u16*)alloc((size_t)DM * DM * 2);
    u16*   WkvT = (u16*)alloc((size_t)2 * DM * DM * 2);
    u16*   WoT  = (u16*)alloc((size_t)DM * DM * 2);
    u16*   Aq   = (u16*)alloc((size_t)CTX * DM * 2);
    u16*   Akv  = (u16*)alloc((size_t)CTX * DM * 2);
    float* ftab = (float*)alloc((size_t)CTX * 64 * 2 * 4);
    u16*   Qf   = (u16*)alloc((size_t)CTX * DM * 2);
    u16*   Kf   = (u16*)alloc((size_t)CTX * DM * 2);
    u16*   vTB  = (u16*)alloc((size_t)CTX * DM * 2);
    u16*   qnB  = (u16*)alloc((size_t)CTX * DM * 2);
    u16*   knB  = (u16*)alloc((size_t)CTX * DM * 2);
    u16*   aB   = (u16*)alloc((size_t)CTX * DM * 2);
    u16*   oprt = (u16*)alloc((size_t)4 * CTX * DM * 2);
    (void)ws_size; (void)in_sizes; (void)n_in; (void)out_size;

    transpose_all_kernel<<<dim3(DM / 32, DM / 32, 4), dim3(32, 8), 0, stream>>>(
        Wq, Wo, Wkv, WqT, WoT, WkvT);

    ln_stats_kernel<<<CTX, 256, 0, stream>>>(x, qng, qnb, kng, knb, Aq, Akv, ftab);

    qkv_gemm256_kernel<<<dim3(384), 256, 0, stream>>>(
        Aq, Akv, WqT, WkvT, bq, bkv, Qf, Kf, vTB);

    const float qk_scale = 0.29730177875068026f;                       // 128^-0.25
    const float fold_q   = 0.08838834764831845f * 1.4426950408889634f; // 1/sqrt(128)*log2(e)
    rot_ln_kernel<<<CTX, 256, 0, stream>>>(
        Qf, Kf, ftab, lng, lnb, qnB, knB, qk_scale, fold_q);

    attn_kernel<<<dim3(CTX / 64, NH), 256, 0, stream>>>(qnB, knB, vTB, aB);

    oproj_gemm256_kernel<<<dim3(256), 512, 0, stream>>>(aB, WoT, oprt);
    combine4_kernel<<<(CTX * DM) / 2048, 256, 0, stream>>>(oprt, bo, out);
}

// Round 11
// 169.196 us; speedup vs baseline: 1.6997x; 1.0365x over previous
//
#include <hip/hip_runtime.h>
#include <stdint.h>
#include <math.h>

#define CTX 2048
#define DM  2048
#define NH  16
#define HD  128

typedef __attribute__((ext_vector_type(8))) short short8;   // 8 x bf16 (4 VGPRs)
typedef __attribute__((ext_vector_type(4))) float f32x4;    // MFMA acc
typedef unsigned short u16;

__device__ __forceinline__ u16 f2bf(float f) {
    unsigned u = __float_as_uint(f);
    unsigned r = u + 0x7fffu + ((u >> 16) & 1u);   // RTNE
    return (u16)(r >> 16);
}
__device__ __forceinline__ float bf2f(u16 h) {
    return __uint_as_float(((unsigned)h) << 16);
}

// Opaque LDS read: invisible to SIInsertWaitcnts' LDS-DMA alias tracking, so
// the compiler cannot insert vmcnt(0) drains before it. Ordering enforced
// manually: counted lgkmcnt + sched_barrier(0) before every consumer (rule #18).
__device__ __forceinline__ short8 ds_read_b128_o(const void* p) {
    short8 r;
    asm volatile("ds_read_b128 %0, %1"
                 : "=v"(r)
                 : "v"((const __attribute__((address_space(3))) void*)p));
    return r;
}

// ------- merged weight transpose + f32->bf16 (W[K][N] -> WT[N][K]), 4 slabs ---
__global__ __launch_bounds__(256)
void transpose_all_kernel(const float* __restrict__ Wq, const float* __restrict__ Wo,
                          const float* __restrict__ Wkv,
                          u16* __restrict__ WqT, u16* __restrict__ WoT, u16* __restrict__ WkvT)
{
    __shared__ float tile[32][33];
    int z = blockIdx.z;
    const float* S; u16* D; int nsrc, c0, r0;
    if (z == 0)      { S = Wq;  D = WqT;  nsrc = DM;     c0 = 0;  r0 = 0;    }
    else if (z == 1) { S = Wo;  D = WoT;  nsrc = DM;     c0 = 0;  r0 = 0;    }
    else if (z == 2) { S = Wkv; D = WkvT; nsrc = 2 * DM; c0 = 0;  r0 = 0;    }
    else             { S = Wkv; D = WkvT; nsrc = 2 * DM; c0 = DM; r0 = DM;   }
    int k0 = blockIdx.x * 32, n0 = blockIdx.y * 32;
    int tx = threadIdx.x, ty = threadIdx.y;          // 32 x 8
#pragma unroll
    for (int j = 0; j < 4; ++j) {
        int kk = ty + 8 * j;
        tile[kk][tx] = S[(size_t)(k0 + kk) * nsrc + c0 + n0 + tx];
    }
    __syncthreads();
#pragma unroll
    for (int j = 0; j < 4; ++j) {
        int nn = ty + 8 * j;
        D[(size_t)(r0 + n0 + nn) * DM + k0 + tx] = f2bf(tile[tx][nn]);
    }
}

// -------- LN stats + normalized A matrices (bf16) + rotary factor table -------
__global__ __launch_bounds__(256)
void ln_stats_kernel(const float* __restrict__ x,
                     const float* __restrict__ qg, const float* __restrict__ qb,
                     const float* __restrict__ kg, const float* __restrict__ kb,
                     u16* __restrict__ Aq, u16* __restrict__ Akv, float* __restrict__ ftab)
{
    int c = blockIdx.x, t = threadIdx.x;
    const float* row = x + (size_t)c * DM;
    float4 v0 = *(const float4*)(row + t * 8);
    float4 v1 = *(const float4*)(row + t * 8 + 4);
    float vals[8] = {v0.x, v0.y, v0.z, v0.w, v1.x, v1.y, v1.z, v1.w};
    float s = 0.f, ss = 0.f;
#pragma unroll
    for (int j = 0; j < 8; ++j) { s += vals[j]; ss += vals[j] * vals[j]; }
#pragma unroll
    for (int off = 32; off; off >>= 1) { s += __shfl_xor(s, off); ss += __shfl_xor(ss, off); }
    __shared__ float red[8];
    int w = t >> 6;
    if ((t & 63) == 0) { red[w] = s; red[4 + w] = ss; }
    __syncthreads();
    float st  = red[0] + red[1] + red[2] + red[3];
    float sst = red[4] + red[5] + red[6] + red[7];
    float mu   = st * (1.f / DM);
    float var  = sst * (1.f / DM) - mu * mu;
    float rstd = rsqrtf(var + 1e-5f);
    if (t < 64) {                         // rotary table, m folded in
        const float LT64 = 10.30895266f / 64.f;   // ln(30000)/64
        float m = sqrtf(sst);
        float sn, cs;
        sincosf((float)c * ((float)t * LT64), &sn, &cs);
        float2 wv = {m * cs, m * sn};
        *(float2*)(ftab + ((size_t)c * 64 + t) * 2) = wv;
    }
    short8 aq, akv;
#pragma unroll
    for (int j = 0; j < 8; ++j) {
        int d = t * 8 + j;
        float xh = (vals[j] - mu) * rstd;
        aq[j]  = (short)f2bf(xh * qg[d] + qb[d]);
        akv[j] = (short)f2bf(xh * kg[d] + kb[d]);
    }
    *(short8*)(Aq  + (size_t)c * DM + t * 8) = aq;
    *(short8*)(Akv + (size_t)c * DM + t * 8) = akv;
}

// ---------------- fused QKV projection GEMM -----------------------------------
// v7: 128x128 tile, BK=64, 4 waves (2Mx2N, 64x64 out/wave), 32 KiB LDS
// single-buffered. Grid 768 blocks (16mt x 16nt x 3seg) -> 3 blocks/CU,
// ~3 waves/SIMD. Rounds 5-6 showed occupancy was GRID-limited (384 blocks =
// 1.5/CU = 1.16 waves/SIMD, and no pipe saturated): this triples the grid so
// cross-block TLP can actually cover the serial stage/lgkm chain. Loop body is
// the proven v5 skeleton with one a-batch (4 m-frags).
__global__ __launch_bounds__(256, 3)
void qkv_gemm256_kernel(const u16* __restrict__ Aq, const u16* __restrict__ Akv,
                        const u16* __restrict__ WqT, const u16* __restrict__ WkvT,
                        const float* __restrict__ bq, const float* __restrict__ bkv,
                        u16* __restrict__ Qf, u16* __restrict__ Kf, u16* __restrict__ vT)
{
    __shared__ __align__(16) u16 As[128][64];         // 16 KiB
    __shared__ __align__(16) u16 Bs[128][64];         // 16 KiB

    constexpr int NT = DM / 64;                       // 32 K-tiles

    // XCD swizzle: 768 blocks, 96 contiguous per XCD (768 % 8 == 0, bijective)
    int lin = blockIdx.x;
    int swz = (lin & 7) * 96 + (lin >> 3);
    int mt  = swz & 15;         // M tile 0..15 (128 rows)
    int ng  = swz >> 4;         // 0..47
    int seg = ng >> 4;          // 0:Q 1:K 2:V
    int nt  = ng & 15;          // N tile 0..15 (128 cols)

    const u16* Amat; const u16* Bmat; const float* bias; u16* outp; bool rowbias;
    if (seg == 0) {
        Amat = Aq  + (size_t)mt * 128 * DM;
        Bmat = WqT + (size_t)nt * 128 * DM;
        bias = bq + nt * 128;
        outp = Qf + (size_t)mt * 128 * DM + nt * 128;
        rowbias = false;
    } else if (seg == 1) {
        Amat = Akv  + (size_t)mt * 128 * DM;
        Bmat = WkvT + (size_t)nt * 128 * DM;
        bias = bkv + nt * 128;
        outp = Kf + (size_t)mt * 128 * DM + nt * 128;
        rowbias = false;
    } else {
        Amat = WkvT + (size_t)(DM + mt * 128) * DM;   // V dims as GEMM rows
        Bmat = Akv  + (size_t)nt * 128 * DM;          // context as GEMM cols
        bias = bkv + DM + mt * 128;                   // per-row bias
        outp = vT + (size_t)mt * 128 * CTX + nt * 128;
        rowbias = true;
    }

    int tid = threadIdx.x;
    int wid = tid >> 6, l = tid & 63;                 // 4 waves, 2M x 2N
    int wr = wid >> 1, wc = wid & 1;
    int lhi = l >> 4, llo = l & 15;
    int srow  = l >> 3;                               // staging row within 8-row group
    int sunit = (l & 7) ^ srow;                       // inverse-swizzled 16B unit

    // stage tile kt: A 128x64 (4 loads/wave) + B 128x64 (4 loads/wave)
    auto stage = [&](int kt) {
#pragma unroll
        for (int rd = 0; rd < 4; ++rd) {
            int r = wid * 32 + rd * 8;
            const u16* srcA = Amat + (size_t)(r + srow) * DM + kt * 64 + sunit * 8;
            __builtin_amdgcn_global_load_lds((const __attribute__((address_space(1))) void*)srcA,
                (__attribute__((address_space(3))) void*)&As[r][0], 16, 0, 0);
        }
#pragma unroll
        for (int rd = 0; rd < 4; ++rd) {
            int r = wid * 32 + rd * 8;
            const u16* srcB = Bmat + (size_t)(r + srow) * DM + kt * 64 + sunit * 8;
            __builtin_amdgcn_global_load_lds((const __attribute__((address_space(1))) void*)srcB,
                (__attribute__((address_space(3))) void*)&Bs[r][0], 16, 0, 0);
        }
    };

    f32x4 acc[4][4] = {};                 // 64 regs accumulator
    short8 a[4][2];                       // 4 m-frags x 2 k-slices
    short8 b0[2][2], b1[2][2];            // ni 0-1 / ni 2-3

    stage(0);
    asm volatile("s_waitcnt vmcnt(0)" ::: "memory");
    __builtin_amdgcn_s_barrier();

    for (int kt = 0; kt < NT; ++kt) {
        // ---- reads: b_lo (4) + a (8) + b_hi (4) -----------------------------
#pragma unroll
        for (int ni = 0; ni < 2; ++ni)
#pragma unroll
            for (int ks = 0; ks < 2; ++ks) {
                int r = 64 * wc + 16 * ni + llo;
                b0[ni][ks] = ds_read_b128_o(&Bs[r][((ks * 4 + lhi) ^ (llo & 7)) << 3]);
            }
#pragma unroll
        for (int mi = 0; mi < 4; ++mi)
#pragma unroll
            for (int ks = 0; ks < 2; ++ks) {
                int r = 64 * wr + 16 * mi + llo;
                a[mi][ks] = ds_read_b128_o(&As[r][((ks * 4 + lhi) ^ (llo & 7)) << 3]);
            }
#pragma unroll
        for (int ni = 0; ni < 2; ++ni)
#pragma unroll
            for (int ks = 0; ks < 2; ++ks) {
                int r = 64 * wc + 16 * (2 + ni) + llo;
                b1[ni][ks] = ds_read_b128_o(&Bs[r][((ks * 4 + lhi) ^ (llo & 7)) << 3]);
            }

        // ---- cluster 1: a x b_lo -------------------------------------------
        asm volatile("s_waitcnt lgkmcnt(4)" ::: "memory");
        __builtin_amdgcn_sched_barrier(0);
        __builtin_amdgcn_s_setprio(1);
#pragma unroll
        for (int ks = 0; ks < 2; ++ks)
#pragma unroll
            for (int mi = 0; mi < 4; ++mi)
#pragma unroll
                for (int ni = 0; ni < 2; ++ni)
                    acc[mi][ni] = __builtin_amdgcn_mfma_f32_16x16x32_bf16(
                        a[mi][ks], b0[ni][ks], acc[mi][ni], 0, 0, 0);
        __builtin_amdgcn_s_setprio(0);

        // ---- cluster 2: a x b_hi -------------------------------------------
        asm volatile("s_waitcnt lgkmcnt(0)" ::: "memory");
        __builtin_amdgcn_sched_barrier(0);
        __builtin_amdgcn_s_setprio(1);
#pragma unroll
        for (int ks = 0; ks < 2; ++ks)
#pragma unroll
            for (int mi = 0; mi < 4; ++mi)
#pragma unroll
                for (int ni = 0; ni < 2; ++ni)
                    acc[mi][2 + ni] = __builtin_amdgcn_mfma_f32_16x16x32_bf16(
                        a[mi][ks], b1[ni][ks], acc[mi][2 + ni], 0, 0, 0);
        __builtin_amdgcn_s_setprio(0);

        // ---- all reads of LDS retired block-wide -> restage -----------------
        __builtin_amdgcn_s_barrier();
        if (kt + 1 < NT) {
            stage(kt + 1);
            asm volatile("s_waitcnt vmcnt(0)" ::: "memory");
            __builtin_amdgcn_s_barrier();
        }
    }

    // ---------------- epilogue: bias + bf16 store ----------------------------
    int cbase = 64 * wc;
    int rbase = 64 * wr;
    if (!rowbias) {
#pragma unroll
        for (int ni = 0; ni < 4; ++ni) {
            float bv = bias[cbase + 16 * ni + llo];
#pragma unroll
            for (int mi = 0; mi < 4; ++mi)
#pragma unroll
                for (int rr = 0; rr < 4; ++rr) {
                    int gr = rbase + 16 * mi + 4 * lhi + rr;
                    outp[(size_t)gr * DM + cbase + 16 * ni + llo] = f2bf(acc[mi][ni][rr] + bv);
                }
        }
    } else {
#pragma unroll
        for (int mi = 0; mi < 4; ++mi)
#pragma unroll
            for (int rr = 0; rr < 4; ++rr) {
                int gr = rbase + 16 * mi + 4 * lhi + rr;
                float bv = bias[gr];
#pragma unroll
                for (int ni = 0; ni < 4; ++ni)
                    outp[(size_t)gr * CTX + cbase + 16 * ni + llo] = f2bf(acc[mi][ni][rr] + bv);
            }
    }
}

// ---------------- O-projection GEMM: 256^2 tile, 4-way split-K ----------------
__global__ __launch_bounds__(512, 2)
void oproj_gemm256_kernel(const u16* __restrict__ A, const u16* __restrict__ BT,
                          u16* __restrict__ outp)
{
    __shared__ __align__(16) u16 As[2][2][128][64];
    __shared__ __align__(16) u16 Bs[2][2][128][64];

    constexpr int NT = 8;                             // 8 K-tiles = 512 deep

    // XCD swizzle: 256 blocks, 32 contiguous per XCD (256 % 8 == 0, bijective)
    int lin = blockIdx.x;
    int swz = (lin & 7) * 32 + (lin >> 3);
    int kz  = swz >> 6;          // K split 0..3
    int rem = swz & 63;
    int mt  = rem & 7;
    int nt  = rem >> 3;

    const u16* Amat = A  + (size_t)mt * 256 * DM + kz * 512;
    const u16* Bmat = BT + (size_t)nt * 256 * DM + kz * 512;
    u16* out = outp + (size_t)kz * CTX * DM + (size_t)mt * 256 * DM + nt * 256;

    int tid = threadIdx.x;
    int wid = tid >> 6, l = tid & 63;
    int wr = wid >> 2, wc = wid & 3;
    int lhi = l >> 4, llo = l & 15;
    int srow  = l >> 3;
    int sunit = (l & 7) ^ srow;

    auto stageA = [&](int kt, int h) {
#pragma unroll
        for (int rd = 0; rd < 2; ++rd) {
            const u16* src = Amat + (size_t)(h * 128 + rd * 64 + wid * 8 + srow) * DM
                             + kt * 64 + sunit * 8;
            __builtin_amdgcn_global_load_lds((const __attribute__((address_space(1))) void*)src,
                (__attribute__((address_space(3))) void*)&As[kt & 1][h][rd * 64 + wid * 8][0],
                16, 0, 0);
        }
    };
    auto stageB = [&](int kt, int h) {
#pragma unroll
        for (int rd = 0; rd < 2; ++rd) {
            const u16* src = Bmat + (size_t)(h * 128 + rd * 64 + wid * 8 + srow) * DM
                             + kt * 64 + sunit * 8;
            __builtin_amdgcn_global_load_lds((const __attribute__((address_space(1))) void*)src,
                (__attribute__((address_space(3))) void*)&Bs[kt & 1][h][rd * 64 + wid * 8][0],
                16, 0, 0);
        }
    };

    f32x4 acc[8][4] = {};
    short8 a[4][2];
    short8 b0[2][2], b1[2][2];
    int bhalf = wc >> 1, brow = (wc & 1) * 64;

    stageA(0, 0); stageA(0, 1); stageB(0, 0); stageB(0, 1);
    stageA(1, 0); stageA(1, 1); stageB(1, 0); stageB(1, 1);
    asm volatile("s_waitcnt vmcnt(8)" ::: "memory");
    __builtin_amdgcn_s_barrier();

    for (int kt = 0; kt < NT; ++kt) {
        int buf = kt & 1;

#pragma unroll
        for (int ni = 0; ni < 2; ++ni)
#pragma unroll
            for (int ks = 0; ks < 2; ++ks) {
                int r = brow + 16 * ni + llo;
                b0[ni][ks] = ds_read_b128_o(&Bs[buf][bhalf][r][((ks * 4 + lhi) ^ (llo & 7)) << 3]);
            }
#pragma unroll
        for (int mi = 0; mi < 4; ++mi)
#pragma unroll
            for (int ks = 0; ks < 2; ++ks) {
                int r = 16 * mi + llo;
                a[mi][ks] = ds_read_b128_o(&As[buf][wr][r][((ks * 4 + lhi) ^ (llo & 7)) << 3]);
            }
#pragma unroll
        for (int ni = 0; ni < 2; ++ni)
#pragma unroll
            for (int ks = 0; ks < 2; ++ks) {
                int r = brow + 16 * (2 + ni) + llo;
                b1[ni][ks] = ds_read_b128_o(&Bs[buf][bhalf][r][((ks * 4 + lhi) ^ (llo & 7)) << 3]);
            }

        asm volatile("s_waitcnt lgkmcnt(4)" ::: "memory");
        __builtin_amdgcn_sched_barrier(0);
        __builtin_amdgcn_s_setprio(1);
#pragma unroll
        for (int ks = 0; ks < 2; ++ks)
#pragma unroll
            for (int mi = 0; mi < 4; ++mi)
#pragma unroll
                for (int ni = 0; ni < 2; ++ni)
                    acc[mi][ni] = __builtin_amdgcn_mfma_f32_16x16x32_bf16(
                        a[mi][ks], b0[ni][ks], acc[mi][ni], 0, 0, 0);
        __builtin_amdgcn_s_setprio(0);

        asm volatile("s_waitcnt lgkmcnt(0)" ::: "memory");
        __builtin_amdgcn_sched_barrier(0);
        __builtin_amdgcn_s_setprio(1);
#pragma unroll
        for (int ks = 0; ks < 2; ++ks)
#pragma unroll
            for (int mi = 0; mi < 4; ++mi)
#pragma unroll
                for (int ni = 0; ni < 2; ++ni)
                    acc[mi][2 + ni] = __builtin_amdgcn_mfma_f32_16x16x32_bf16(
                        a[mi][ks], b1[ni][ks], acc[mi][2 + ni], 0, 0, 0);
        __builtin_amdgcn_s_setprio(0);

        __builtin_amdgcn_s_barrier();   // #1

        if (kt + 2 < NT) { stageB(kt + 2, 0); stageB(kt + 2, 1); }
#pragma unroll
        for (int mi = 0; mi < 4; ++mi)
#pragma unroll
            for (int ks = 0; ks < 2; ++ks) {
                int r = 16 * (4 + mi) + llo;
                a[mi][ks] = ds_read_b128_o(&As[buf][wr][r][((ks * 4 + lhi) ^ (llo & 7)) << 3]);
            }

        asm volatile("s_waitcnt lgkmcnt(0)" ::: "memory");
        __builtin_amdgcn_sched_barrier(0);
        __builtin_amdgcn_s_setprio(1);
#pragma unroll
        for (int ks = 0; ks < 2; ++ks)
#pragma unroll
            for (int mi = 0; mi < 4; ++mi)
#pragma unroll
                for (int ni = 0; ni < 2; ++ni)
                    acc[4 + mi][2 + ni] = __builtin_amdgcn_mfma_f32_16x16x32_bf16(
                        a[mi][ks], b1[ni][ks], acc[4 + mi][2 + ni], 0, 0, 0);
        __builtin_amdgcn_s_setprio(0);

        __builtin_amdgcn_s_barrier();   // #2

        if (kt + 2 < NT) { stageA(kt + 2, 0); stageA(kt + 2, 1); }
        __builtin_amdgcn_s_setprio(1);
#pragma unroll
        for (int ks = 0; ks < 2; ++ks)
#pragma unroll
            for (int mi = 0; mi < 4; ++mi)
#pragma unroll
                for (int ni = 0; ni < 2; ++ni)
                    acc[4 + mi][ni] = __builtin_amdgcn_mfma_f32_16x16x32_bf16(
                        a[mi][ks], b0[ni][ks], acc[4 + mi][ni], 0, 0, 0);
        __builtin_amdgcn_s_setprio(0);

        if (kt + 2 < NT)      { asm volatile("s_waitcnt vmcnt(8)" ::: "memory"); }
        else if (kt + 1 < NT) { asm volatile("s_waitcnt vmcnt(0)" ::: "memory"); }
        __builtin_amdgcn_s_barrier();   // #3
    }

    int rbase = 128 * wr;
    int cbase = 64 * wc;
#pragma unroll
    for (int ni = 0; ni < 4; ++ni) {
#pragma unroll
        for (int mi = 0; mi < 8; ++mi)
#pragma unroll
            for (int rr = 0; rr < 4; ++rr) {
                int gr = rbase + 16 * mi + 4 * lhi + rr;
                out[(size_t)gr * DM + cbase + 16 * ni + llo] = f2bf(acc[mi][ni][rr]);
            }
    }
}

// -------- table-driven rotary + per-head LN (one block per token row) ---------
__global__ __launch_bounds__(256)
void rot_ln_kernel(const u16* __restrict__ Qf, const u16* __restrict__ Kf,
                   const float* __restrict__ ftab,
                   const float* __restrict__ g, const float* __restrict__ b,
                   u16* __restrict__ qnB, u16* __restrict__ knB,
                   float qk_scale, float fold_q)
{
    int c = blockIdx.x, t = threadIdx.x;
    int h  = t >> 4;
    int dl = (t & 15) * 8;
    const float* tab = ftab + ((size_t)c * 64 + (dl >> 1)) * 2;
    float fre[4], fim[4];
#pragma unroll
    for (int p = 0; p < 4; ++p) { fre[p] = tab[2 * p]; fim[p] = tab[2 * p + 1]; }
    float gv[8], bv2[8];
#pragma unroll
    for (int j = 0; j < 8; ++j) { gv[j] = g[dl + j]; bv2[j] = b[dl + j]; }

#pragma unroll
    for (int z = 0; z < 2; ++z) {
        const u16* src = z ? Kf : Qf;
        u16* dst = z ? knB : qnB;
        float fold = z ? 1.f : fold_q;
        short8 vv = *(const short8*)(src + (size_t)c * DM + t * 8);
        float o[8];
        float s = 0.f, ss = 0.f;
#pragma unroll
        for (int p = 0; p < 4; ++p) {
            float a  = bf2f((u16)vv[2 * p])     * qk_scale;
            float b2 = bf2f((u16)vv[2 * p + 1]) * qk_scale;
            float o0 = a * fre[p] - b2 * fim[p];
            float o1 = a * fim[p] + b2 * fre[p];
            o[2 * p] = o0; o[2 * p + 1] = o1;
            s += o0 + o1;
            ss += o0 * o0 + o1 * o1;
        }
#pragma unroll
        for (int off = 1; off < 16; off <<= 1) {
            s += __shfl_xor(s, off);
            ss += __shfl_xor(ss, off);
        }
        float mu   = s * (1.f / HD);
        float var  = ss * (1.f / HD) - mu * mu;
        float rstd = rsqrtf(var + 1e-5f);
        short8 r;
#pragma unroll
        for (int j = 0; j < 8; ++j)
            r[j] = (short)f2bf(((o[j] - mu) * rstd * gv[j] + bv2[j]) * fold);
        *(short8*)(dst + ((size_t)h * CTX + c) * HD + dl) = r;
    }
}

// ---------------- causal flash attention v6 ------------------------------------
// v5 + V-prefetch (round-10, kept: small but real win). All Kb/Vb/p_lds reads
// opaque with counted lgkm waits; only vmcnt(0) is the end-of-iter syncthreads.
__global__ __launch_bounds__(256, 2)
void attn_kernel(const u16* __restrict__ qn, const u16* __restrict__ kn,
                 const u16* __restrict__ vT, u16* __restrict__ aout)
{
    __shared__ __align__(16) u16 Kb[2][64][128];
    __shared__ __align__(16) u16 Vb[2][128][64];
    __shared__ __align__(16) u16 p_lds[4][16][72];

    int h  = blockIdx.y;
    int xs = blockIdx.x;
    int qb = (h >= 8) ? (31 - xs) : xs;   // CU load-balance pairing
    int q0 = qb * 64;
    int tid = threadIdx.x, w = tid >> 6, l = tid & 63;
    int lhi = l >> 4, llo = l & 15;

    const u16* qrow = qn + ((size_t)h * CTX + q0 + 16 * w + llo) * HD + 8 * lhi;
    short8 qf[4];
#pragma unroll
    for (int ks = 0; ks < 4; ++ks) qf[ks] = *(const short8*)(qrow + 32 * ks);

    auto stage = [&](int buf, int kv0) {
        int rb = 16 * w;
#pragma unroll
        for (int j = 0; j < 4; ++j) {
            int r = rb + 4 * j + (l >> 4);
            int csw = (l & 15) ^ (r & 15);
            const u16* src = kn + ((size_t)h * CTX + kv0 + r) * HD + (csw << 3);
            __builtin_amdgcn_global_load_lds((const __attribute__((address_space(1))) void*)src,
                (__attribute__((address_space(3))) void*)&Kb[buf][rb + 4 * j][0], 16, 0, 0);
        }
        int db = 32 * w;
#pragma unroll
        for (int j = 0; j < 4; ++j) {
            int d = db + 8 * j + (l >> 3);
            int csw = (l & 7) ^ (d & 7);
            const u16* src = vT + ((size_t)h * HD + d) * CTX + kv0 + (csw << 3);
            __builtin_amdgcn_global_load_lds((const __attribute__((address_space(1))) void*)src,
                (__attribute__((address_space(3))) void*)&Vb[buf][db + 8 * j][0], 16, 0, 0);
        }
    };

    float m_s = -1e30f, l_p = 0.f;
    f32x4 o_acc[8];
#pragma unroll
    for (int ni = 0; ni < 8; ++ni) o_acc[ni] = (f32x4){0.f, 0.f, 0.f, 0.f};

    stage(0, 0);
    __syncthreads();

    int cur = 0;
    for (int jt = 0; jt <= qb; ++jt) {
        if (jt < qb) stage(cur ^ 1, (jt + 1) * 64);   // prefetch overlaps compute

        // ---- QK^T: opaque reads, 2 pipelined K banks ------------------------
        f32x4 sacc[4] = {};
        short8 kf0[4], kf1[4];
#pragma unroll
        for (int ni = 0; ni < 4; ++ni)
            kf0[ni] = ds_read_b128_o(&Kb[cur][16 * ni + llo][(lhi ^ llo) << 3]);
#pragma unroll
        for (int ni = 0; ni < 4; ++ni)
            kf1[ni] = ds_read_b128_o(&Kb[cur][16 * ni + llo][((4 + lhi) ^ llo) << 3]);

        asm volatile("s_waitcnt lgkmcnt(4)" ::: "memory");   // kf0 ready
        __builtin_amdgcn_sched_barrier(0);
        __builtin_amdgcn_s_setprio(1);
#pragma unroll
        for (int ni = 0; ni < 4; ++ni)
            sacc[ni] = __builtin_amdgcn_mfma_f32_16x16x32_bf16(kf0[ni], qf[0], sacc[ni], 0, 0, 0);
        __builtin_amdgcn_s_setprio(0);

#pragma unroll
        for (int ni = 0; ni < 4; ++ni)
            kf0[ni] = ds_read_b128_o(&Kb[cur][16 * ni + llo][((8 + lhi) ^ llo) << 3]);
        asm volatile("s_waitcnt lgkmcnt(4)" ::: "memory");   // kf1 ready
        __builtin_amdgcn_sched_barrier(0);
        __builtin_amdgcn_s_setprio(1);
#pragma unroll
        for (int ni = 0; ni < 4; ++ni)
            sacc[ni] = __builtin_amdgcn_mfma_f32_16x16x32_bf16(kf1[ni], qf[1], sacc[ni], 0, 0, 0);
        __builtin_amdgcn_s_setprio(0);

#pragma unroll
        for (int ni = 0; ni < 4; ++ni)
            kf1[ni] = ds_read_b128_o(&Kb[cur][16 * ni + llo][((12 + lhi) ^ llo) << 3]);
        asm volatile("s_waitcnt lgkmcnt(4)" ::: "memory");   // kf0 (ks=2) ready
        __builtin_amdgcn_sched_barrier(0);
        __builtin_amdgcn_s_setprio(1);
#pragma unroll
        for (int ni = 0; ni < 4; ++ni)
            sacc[ni] = __builtin_amdgcn_mfma_f32_16x16x32_bf16(kf0[ni], qf[2], sacc[ni], 0, 0, 0);
        __builtin_amdgcn_s_setprio(0);

        asm volatile("s_waitcnt lgkmcnt(0)" ::: "memory");   // kf1 (ks=3) ready
        __builtin_amdgcn_sched_barrier(0);
        __builtin_amdgcn_s_setprio(1);
#pragma unroll
        for (int ni = 0; ni < 4; ++ni)
            sacc[ni] = __builtin_amdgcn_mfma_f32_16x16x32_bf16(kf1[ni], qf[3], sacc[ni], 0, 0, 0);
        __builtin_amdgcn_s_setprio(0);

        // ---- V prefetch: issue all 16 V reads; they retire under softmax ----
        short8 vfA[8], vfB[8];
#pragma unroll
        for (int ni = 0; ni < 8; ++ni)
            vfA[ni] = ds_read_b128_o(&Vb[cur][16 * ni + llo][(lhi ^ (llo & 7)) << 3]);
#pragma unroll
        for (int ni = 0; ni < 8; ++ni)
            vfB[ni] = ds_read_b128_o(&Vb[cur][16 * ni + llo][((4 + lhi) ^ (llo & 7)) << 3]);

        if (jt == qb) {                  // causal mask inside diagonal tile
            int qloc = 16 * w + llo;
#pragma unroll
            for (int ni = 0; ni < 4; ++ni)
#pragma unroll
                for (int r = 0; r < 4; ++r)
                    if (16 * ni + 4 * lhi + r > qloc) sacc[ni][r] = -INFINITY;
        }

        // speculative P with OLD running max (no cross-lane wait)
        float pv[16];
#pragma unroll
        for (int ni = 0; ni < 4; ++ni)
#pragma unroll
            for (int r = 0; r < 4; ++r) pv[4 * ni + r] = exp2f(sacc[ni][r] - m_s);

        // per-lane local max only; __any supplies the cross-lane OR
        float mx = sacc[0][0];
#pragma unroll
        for (int ni = 0; ni < 4; ++ni)
#pragma unroll
            for (int r = 0; r < 4; ++r) mx = fmaxf(mx, sacc[ni][r]);

        if (__any(mx > m_s + 8.f)) {     // rare path: full reduce + rescale
            mx = fmaxf(mx, __shfl_xor(mx, 16));
            mx = fmaxf(mx, __shfl_xor(mx, 32));
            float mnew = fmaxf(m_s, mx);
            float fac = exp2f(m_s - mnew);
#pragma unroll
            for (int r = 0; r < 4; ++r) {
                float fr = __shfl(fac, 4 * lhi + r);
#pragma unroll
                for (int ni = 0; ni < 8; ++ni) o_acc[ni][r] *= fr;
            }
#pragma unroll
            for (int ni = 0; ni < 4; ++ni)
#pragma unroll
                for (int r = 0; r < 4; ++r) pv[4 * ni + r] = exp2f(sacc[ni][r] - mnew);
            l_p *= fac;
            m_s = mnew;
        }

        // pack P -> p_lds (wave-private region; DS pipe is in-order per wave)
#pragma unroll
        for (int ni = 0; ni < 4; ++ni)
#pragma unroll
            for (int hf = 0; hf < 2; ++hf) {
                unsigned pk;
                asm("v_cvt_pk_bf16_f32 %0, %1, %2" : "=v"(pk)
                    : "v"(pv[4 * ni + 2 * hf]), "v"(pv[4 * ni + 2 * hf + 1]));
                *(unsigned*)&p_lds[w][llo][16 * ni + 4 * lhi + 2 * hf] = pk;
            }

        // deferred l: per-lane partial only (cross-lane reduce in epilogue)
        float ps = 0.f;
#pragma unroll
        for (int j = 0; j < 16; ++j) ps += pv[j];
        l_p += ps;

        // pin pack-writes in program order before the opaque pa reads
        __builtin_amdgcn_sched_barrier(0);

        // ---- O += P . V; counted waits (retire order: vf, writes, pa0, pa1) -
        short8 pa0 = ds_read_b128_o(&p_lds[w][llo][8 * lhi]);
        short8 pa1 = ds_read_b128_o(&p_lds[w][llo][32 + 8 * lhi]);

        asm volatile("s_waitcnt lgkmcnt(1)" ::: "memory");   // all but pa1
        __builtin_amdgcn_sched_barrier(0);
        __builtin_amdgcn_s_setprio(1);
#pragma unroll
        for (int ni = 0; ni < 8; ++ni)
            o_acc[ni] = __builtin_amdgcn_mfma_f32_16x16x32_bf16(pa0, vfA[ni], o_acc[ni], 0, 0, 0);
        __builtin_amdgcn_s_setprio(0);

        asm volatile("s_waitcnt lgkmcnt(0)" ::: "memory");   // pa1
        __builtin_amdgcn_sched_barrier(0);
        __builtin_amdgcn_s_setprio(1);
#pragma unroll
        for (int ni = 0; ni < 8; ++ni)
            o_acc[ni] = __builtin_amdgcn_mfma_f32_16x16x32_bf16(pa1, vfB[ni], o_acc[ni], 0, 0, 0);
        __builtin_amdgcn_s_setprio(0);

        __syncthreads();   // drains prefetch vmcnt + frees buf[cur]
        cur ^= 1;
    }

    float lsum = l_p;
    lsum += __shfl_xor(lsum, 16);
    lsum += __shfl_xor(lsum, 32);
#pragma unroll
    for (int r = 0; r < 4; ++r) {
        float lr  = __shfl(lsum, 4 * lhi + r);
        float inv = 1.f / lr;
        int qrow2 = q0 + 16 * w + 4 * lhi + r;
#pragma unroll
        for (int ni = 0; ni < 8; ++ni)
            aout[(size_t)qrow2 * DM + h * HD + 16 * ni + llo] = f2bf(o_acc[ni][r] * inv);
    }
}

// ---------------- combine 4 bf16 split-K partials + bias ----------------------
__global__ __launch_bounds__(256)
void combine4_kernel(const u16* __restrict__ p, const float* __restrict__ bias,
                     float* __restrict__ out)
{
    size_t i = ((size_t)blockIdx.x * 256 + threadIdx.x) * 8;
    short8 a0 = *(const short8*)(p + i);
    short8 a1 = *(const short8*)(p + (size_t)CTX * DM + i);
    short8 a2 = *(const short8*)(p + 2 * (size_t)CTX * DM + i);
    short8 a3 = *(const short8*)(p + 3 * (size_t)CTX * DM + i);
    int dbase = (int)(i & (DM - 1));
    float4 bv0 = *(const float4*)(bias + dbase);
    float4 bv1 = *(const float4*)(bias + dbase + 4);
    float r[8];
    float bvv[8] = {bv0.x, bv0.y, bv0.z, bv0.w, bv1.x, bv1.y, bv1.z, bv1.w};
#pragma unroll
    for (int j = 0; j < 8; ++j)
        r[j] = (bf2f((u16)a0[j]) + bf2f((u16)a1[j]))
             + (bf2f((u16)a2[j]) + bf2f((u16)a3[j])) + bvv[j];
    *(float4*)(out + i)     = (float4){r[0], r[1], r[2], r[3]};
    *(float4*)(out + i + 4) = (float4){r[4], r[5], r[6], r[7]};
}

// ------------------------------- launcher ------------------------------------
extern "C" void kernel_launch(void* const* d_in, const int* in_sizes, int n_in,
                              void* d_out, int out_size, void* d_ws, size_t ws_size,
                              hipStream_t stream)
{
    const float* x   = (const float*)d_in[0];
    const float* qng = (const float*)d_in[1];
    const float* qnb = (const float*)d_in[2];
    const float* kng = (const float*)d_in[3];
    const float* knb = (const float*)d_in[4];
    const float* Wq  = (const float*)d_in[5];
    const float* bq  = (const float*)d_in[6];
    const float* Wkv = (const float*)d_in[7];
    const float* bkv = (const float*)d_in[8];
    const float* Wo  = (const float*)d_in[9];
    const float* bo  = (const float*)d_in[10];
    const float* lng = (const float*)d_in[11];
    const float* lnb = (const float*)d_in[12];
    float* out = (float*)d_out;

    uint8_t* ws = (uint8_t*)d_ws;
    size_t off = 0;
    auto alloc = [&](size_t bytes) -> void* {
        void* p = ws + off;
        off += (bytes + 255) & ~(size_t)255;
        return p;
    };
    u16*   WqT  = (u16*)alloc((size_t)DM * DM * 2);
    u16*   WkvT = (u16*)alloc((size_t)2 * DM * DM * 2);
    u16*   WoT  = (u16*)alloc((size_t)DM * DM * 2);
    u16*   Aq   = (u16*)alloc((size_t)CTX * DM * 2);
    u16*   Akv  = (u16*)alloc((size_t)CTX * DM * 2);
    float* ftab = (float*)alloc((size_t)CTX * 64 * 2 * 4);
    u16*   Qf   = (u16*)alloc((size_t)CTX * DM * 2);
    u16*   Kf   = (u16*)alloc((size_t)CTX * DM * 2);
    u16*   vTB  = (u16*)alloc((size_t)CTX * DM * 2);
    u16*   qnB  = (u16*)alloc((size_t)CTX * DM * 2);
    u16*   knB  = (u16*)alloc((size_t)CTX * DM * 2);
    u16*   aB   = (u16*)alloc((size_t)CTX * DM * 2);
    u16*   oprt = (u16*)alloc((size_t)4 * CTX * DM * 2);
    (void)ws_size; (void)in_sizes; (void)n_in; (void)out_size;

    transpose_all_kernel<<<dim3(DM / 32, DM / 32, 4), dim3(32, 8), 0, stream>>>(
        Wq, Wo, Wkv, WqT, WoT, WkvT);

    ln_stats_kernel<<<CTX, 256, 0, stream>>>(x, qng, qnb, kng, knb, Aq, Akv, ftab);

    qkv_gemm256_kernel<<<dim3(768), 256, 0, stream>>>(
        Aq, Akv, WqT, WkvT, bq, bkv, Qf, Kf, vTB);

    const float qk_scale = 0.29730177875068026f;                       // 128^-0.25
    const float fold_q   = 0.08838834764831845f * 1.4426950408889634f; // 1/sqrt(128)*log2(e)
    rot_ln_kernel<<<CTX, 256, 0, stream>>>(
        Qf, Kf, ftab, lng, lnb, qnB, knB, qk_scale, fold_q);

    attn_kernel<<<dim3(CTX / 64, NH), 256, 0, stream>>>(qnB, knB, vTB, aB);

    oproj_gemm256_kernel<<<dim3(256), 512, 0, stream>>>(aB, WoT, oprt);
    combine4_kernel<<<(CTX * DM) / 2048, 256, 0, stream>>>(oprt, bo, out);
}